// Round 11
// baseline (464.038 us; speedup 1.0000x reference)
//
#include <hip/hip_runtime.h>
#include <hip/hip_bf16.h>

// Problem constants
#define T_LEN 4096
#define HID_DIM 2048
#define NH 16
#define DNOPE 128
#define DROPE 64
#define DV 128
#define LKV 512
#define DQK 192   // DNOPE + DROPE

#define BN 64     // flash k-tile width

typedef __attribute__((ext_vector_type(8))) __bf16 bf16x8;
typedef __attribute__((ext_vector_type(4))) float f32x4;
typedef __attribute__((ext_vector_type(4))) short s16x4;

__device__ __forceinline__ unsigned short f2b(float f) {
  unsigned u = __builtin_bit_cast(unsigned, f);
  unsigned r = (u + 0x7FFFu + ((u >> 16) & 1u)) >> 16;
  return (unsigned short)r;
}

#define GL2LDS16(gp, lp)                                                   \
  __builtin_amdgcn_global_load_lds(                                        \
      (const __attribute__((address_space(1))) unsigned int*)(gp),         \
      (__attribute__((address_space(3))) unsigned int*)(lp), 16, 0, 0)

// K=16 PV mfma: B-operand layout (n=l16, k=quad*4+j) == S^T C-layout -> zero transpose.
#if __has_builtin(__builtin_amdgcn_mfma_f32_16x16x16bf16_1k)
#define HAVE_MFMA16 1
__device__ __forceinline__ f32x4 mfma16(s16x4 a, s16x4 b, f32x4 c) {
  return __builtin_amdgcn_mfma_f32_16x16x16bf16_1k(a, b, c, 0, 0, 0);
}
#elif __has_builtin(__builtin_amdgcn_mfma_f32_16x16x16_bf16)
#define HAVE_MFMA16 1
typedef __attribute__((ext_vector_type(4))) __bf16 bf16x4v;
__device__ __forceinline__ f32x4 mfma16(s16x4 a, s16x4 b, f32x4 c) {
  return __builtin_amdgcn_mfma_f32_16x16x16_bf16(
      __builtin_bit_cast(bf16x4v, a), __builtin_bit_cast(bf16x4v, b), c, 0, 0, 0);
}
#else
#define HAVE_MFMA16 0
#endif

// XCD-aware bijective block swizzle (T1): consecutive linear ids chunk onto one XCD so
// blocks sharing A/B panels hit the same L2. Requires nwg % 8 == 0 (all our GEMM grids).
__device__ __forceinline__ void xcd_swz(int nbx, int* bx, int* by) {
  int lin = blockIdx.y * nbx + blockIdx.x;
  int cpx = (nbx * gridDim.y) >> 3;
  int swz = (lin & 7) * cpx + (lin >> 3);
  *bx = swz % nbx;
  *by = swz / nbx;
}

// ---------------- all 4 weight transposes + fused hs f32->bf16 cvt (one launch) ----------
// bid >= 13440: vectorized cvt of hidden_states (4096 blocks x 256 thr x 8 elem = 8.4M).
// R11: transpose WRITE side re-mapped so each thread packs 4 consecutive output elements
// (one column, 4 input rows) into one 8B uint2 store (was 4 scalar 2B stores).
// Mapping check: out[(c0+a)*R + r0+b] = t[b][a] with a = co = u>>3, b = rg*4+q (u = tid).
// Alignment: r0+rg*4 mult-4 -> 8B aligned. LDS read bank = (rg*4+q+co)%32 -> 2-way (free).
__global__ void k_transpose_all(const float* __restrict__ Wq, const float* __restrict__ Wkva,
                                const float* __restrict__ Wkvb, const float* __restrict__ Wo,
                                const float* __restrict__ hs,
                                unsigned short* __restrict__ WqT, unsigned short* __restrict__ WkvaT,
                                unsigned short* __restrict__ WkvbT, unsigned short* __restrict__ WoT,
                                unsigned short* __restrict__ hsb) {
  int bid = blockIdx.x;
  int tx = threadIdx.x, ty = threadIdx.y;
  if (bid >= 13440) {
    int i = (bid - 13440) * 256 + ty * 32 + tx;   // thread index over 1,048,576
    const float4* in4 = (const float4*)hs;
    float4 v0 = in4[i * 2];
    float4 v1 = in4[i * 2 + 1];
    unsigned a = (unsigned)f2b(v0.x) | ((unsigned)f2b(v0.y) << 16);
    unsigned b = (unsigned)f2b(v0.z) | ((unsigned)f2b(v0.w) << 16);
    unsigned c = (unsigned)f2b(v1.x) | ((unsigned)f2b(v1.y) << 16);
    unsigned d = (unsigned)f2b(v1.z) | ((unsigned)f2b(v1.w) << 16);
    uint4 pk = {a, b, c, d};
    ((uint4*)hsb)[i] = pk;
    return;
  }
  __shared__ float t[32][33];
  const float* in; unsigned short* out; int R, C, bx, by;
  if (bid < 6144)      { in = Wq;   out = WqT;   R = 2048; C = 3072; bx = bid % 96;  by = bid / 96; }
  else if (bid < 7296) { int b = bid - 6144; in = Wkva; out = WkvaT; R = 2048; C = 576;  bx = b % 18;  by = b / 18; }
  else if (bid < 9344) { int b = bid - 7296; in = Wkvb; out = WkvbT; R = 512;  C = 4096; bx = b % 128; by = b / 128; }
  else                 { int b = bid - 9344; in = Wo;   out = WoT;   R = 2048; C = 2048; bx = b % 64;  by = b / 64; }
  int c0 = bx * 32, r0 = by * 32;
#pragma unroll
  for (int k = 0; k < 4; k++)
    t[ty + 8 * k][tx] = in[(size_t)(r0 + ty + 8 * k) * C + c0 + tx];
  __syncthreads();
  int u = ty * 32 + tx;
  int co = u >> 3;          // 0..31: column within tile (= output row c0+co)
  int rg = u & 7;           // 0..7:  group of 4 output cols (= input rows r0+rg*4..+3)
  unsigned lo = (unsigned)f2b(t[rg * 4 + 0][co]) | ((unsigned)f2b(t[rg * 4 + 1][co]) << 16);
  unsigned hi = (unsigned)f2b(t[rg * 4 + 2][co]) | ((unsigned)f2b(t[rg * 4 + 3][co]) << 16);
  uint2 pk = {lo, hi};
  *(uint2*)&out[(size_t)(c0 + co) * R + r0 + rg * 4] = pk;
}

// ------------- m97-style 128x128 LDS-staged MFMA GEMM core as a macro body --------------
#define GEMM_CORE(Aptr, Btptr, Nn, Kk, ldaa, ldbb)                                         \
  __shared__ unsigned short As[128 * 32];                                                  \
  __shared__ unsigned short Bs[128 * 32];                                                  \
  int tid = threadIdx.x;                                                                   \
  int lane = tid & 63, w = tid >> 6;                                                       \
  int quad = lane >> 4, l16 = lane & 15;                                                   \
  int wm = (w >> 1) * 64, wn = (w & 1) * 64;                                               \
  int i0 = tid, i1 = tid + 256;                                                            \
  int rA0 = i0 >> 2, rA1 = i1 >> 2;                                                       \
  int c80 = (i0 & 3) * 8, c81 = (i1 & 3) * 8;                                              \
  const unsigned short* Ag0 = (Aptr) + (size_t)(m0 + rA0) * (ldaa) + c80;                  \
  const unsigned short* Ag1 = (Aptr) + (size_t)(m0 + rA1) * (ldaa) + c81;                  \
  int bR0 = n0 + rA0; if (bR0 >= (Nn)) bR0 = (Nn) - 1;                                     \
  int bR1 = n0 + rA1; if (bR1 >= (Nn)) bR1 = (Nn) - 1;                                     \
  const unsigned short* Bg0 = (Btptr) + (size_t)bR0 * (ldbb) + c80;                        \
  const unsigned short* Bg1 = (Btptr) + (size_t)bR1 * (ldbb) + c81;                        \
  f32x4 acc[4][4] = {};                                                                    \
  for (int k0 = 0; k0 < (Kk); k0 += 32) {                                                  \
    GL2LDS16(Ag0 + k0, &As[i0 * 8]);                                                       \
    GL2LDS16(Ag1 + k0, &As[i1 * 8]);                                                       \
    GL2LDS16(Bg0 + k0, &Bs[i0 * 8]);                                                       \
    GL2LDS16(Bg1 + k0, &Bs[i1 * 8]);                                                       \
    __syncthreads();                                                                       \
    bf16x8 aF[4], bF[4];                                                                   \
    _Pragma("unroll")                                                                      \
    for (int i = 0; i < 4; i++)                                                            \
      aF[i] = *(const bf16x8*)&As[(wm + i * 16 + l16) * 32 + quad * 8];                    \
    _Pragma("unroll")                                                                      \
    for (int j = 0; j < 4; j++)                                                            \
      bF[j] = *(const bf16x8*)&Bs[(wn + j * 16 + l16) * 32 + quad * 8];                    \
    _Pragma("unroll")                                                                      \
    for (int i = 0; i < 4; i++)                                                            \
      _Pragma("unroll")                                                                    \
      for (int j = 0; j < 4; j++)                                                          \
        acc[i][j] = __builtin_amdgcn_mfma_f32_16x16x32_bf16(aF[i], bF[j], acc[i][j], 0, 0, 0); \
    __syncthreads();                                                                       \
  }                                                                                        \
  int row0 = m0 + wm + quad * 4; (void)row0;

// ---------------- plain GEMM -> f32 C ----------------------------------------------------
__global__ __launch_bounds__(256) void k_gemm128(
    const unsigned short* __restrict__ A, const unsigned short* __restrict__ Bt,
    float* __restrict__ Cf, int N, int K, int lda, int ldb, int ldc) {
  int bxs, bys; xcd_swz(gridDim.x, &bxs, &bys);
  int m0 = bys * 128, n0 = bxs * 128;
  GEMM_CORE(A, Bt, N, K, lda, ldb)
#pragma unroll
  for (int i = 0; i < 4; i++)
#pragma unroll
    for (int j = 0; j < 4; j++) {
      int col = n0 + wn + j * 16 + l16;
      if (col < N)
#pragma unroll
        for (int r = 0; r < 4; r++)
          Cf[(size_t)(row0 + i * 16 + r) * ldc + col] = acc[i][j][r];
    }
}

// ---------------- merged Wq + Wkva projection (one launch, 29x32 grid) -------------------
// bx < 24: Wq tile with fused rope+scale -> Qh; bx >= 24: Wkva tile -> latentf f32.
__global__ __launch_bounds__(256) void k_gemm_proj(
    const unsigned short* __restrict__ A, const unsigned short* __restrict__ WqT,
    const unsigned short* __restrict__ WkvaT, const int* __restrict__ pos,
    unsigned short* __restrict__ Qh, float* __restrict__ latentf) {
  int bxx, byy; xcd_swz(gridDim.x, &bxx, &byy);
  bool iswq = bxx < 24;
  const unsigned short* Bt = iswq ? WqT : WkvaT;
  int N = iswq ? NH * DQK : (LKV + DROPE);
  int m0 = byy * 128, n0 = (iswq ? bxx : bxx - 24) * 128;
  GEMM_CORE(A, Bt, N, HID_DIM, HID_DIM, HID_DIM)
  if (iswq) {
    const float scale = 0.07216878364870323f;  // 1/sqrt(192)
    int b64 = (n0 + wn) >> 6;
    int h = b64 / 3, rem3 = b64 - 3 * h;
    unsigned short* Qb = Qh + (size_t)h * T_LEN * DQK;
    if (rem3 < 2) {
#pragma unroll
      for (int i = 0; i < 4; i++)
#pragma unroll
        for (int r = 0; r < 4; r++) {
          int t = row0 + i * 16 + r;
#pragma unroll
          for (int j = 0; j < 4; j++)
            Qb[(size_t)t * DQK + rem3 * 64 + j * 16 + l16] = f2b(acc[i][j][r] * scale);
        }
    } else {
      // rope branch: inv depends only on lane (idx = j*16+l16) -> hoist out of i/r loops
      float inv0 = __expf((float)l16 * -0.2878231366242557f);          // j=0
      float inv1 = __expf((float)(16 + l16) * -0.2878231366242557f);   // j=1
#pragma unroll
      for (int i = 0; i < 4; i++)
#pragma unroll
        for (int r = 0; r < 4; r++) {
          int t = row0 + i * 16 + r;
          float p = (float)pos[t];
#pragma unroll
          for (int j = 0; j < 2; j++) {
            int idx = j * 16 + l16;
            float inv = (j == 0) ? inv0 : inv1;
            float sn, cs;
            __sincosf(p * inv, &sn, &cs);
            float x1 = acc[i][j][r] * scale, x2 = acc[i][j + 2][r] * scale;
            Qb[(size_t)t * DQK + DNOPE + idx]      = f2b(x1 * cs - x2 * sn);
            Qb[(size_t)t * DQK + DNOPE + 32 + idx] = f2b(x2 * cs + x1 * sn);
          }
        }
    }
  } else {
#pragma unroll
    for (int i = 0; i < 4; i++)
#pragma unroll
      for (int j = 0; j < 4; j++) {
        int col = n0 + wn + j * 16 + l16;
        if (col < LKV + DROPE)
#pragma unroll
          for (int r = 0; r < 4; r++)
            latentf[(size_t)(row0 + i * 16 + r) * (LKV + DROPE) + col] = acc[i][j][r];
      }
  }
}

// ---------------- Wkvb GEMM with fused scatter -> Kh nope / V^T --------------------------
// VT epilogue packs the 4 t-consecutive values into one 8B uint2 store (t0 is 4-aligned).
// The c<128 branch is wave-uniform: c-runs are 16-aligned and never straddle 128.
__global__ __launch_bounds__(256) void k_gemm_wkvb(
    const unsigned short* __restrict__ A, const unsigned short* __restrict__ Bt,
    unsigned short* __restrict__ Kh, unsigned short* __restrict__ VT) {
  int bxs, bys; xcd_swz(gridDim.x, &bxs, &bys);
  int m0 = bys * 128, n0 = bxs * 128;
  GEMM_CORE(A, Bt, NH * 256, LKV, LKV, LKV)
#pragma unroll
  for (int i = 0; i < 4; i++)
#pragma unroll
    for (int j = 0; j < 4; j++) {
      int col = n0 + wn + j * 16 + l16;
      int h = col >> 8, c = col & 255;
      int t0 = row0 + i * 16;
      if (c < 128) {
#pragma unroll
        for (int r = 0; r < 4; r++)
          Kh[((size_t)h * T_LEN + t0 + r) * DQK + c] = f2b(acc[i][j][r]);
      } else {
        unsigned lo = (unsigned)f2b(acc[i][j][0]) | ((unsigned)f2b(acc[i][j][1]) << 16);
        unsigned hi = (unsigned)f2b(acc[i][j][2]) | ((unsigned)f2b(acc[i][j][3]) << 16);
        uint2 pk = {lo, hi};
        *(uint2*)&VT[(size_t)(h * 128 + c - 128) * T_LEN + t0] = pk;
      }
    }
}

// ---------------- latent f32 [T][576] -> kv_a bf16 [T][512] (rmsnorm) + Kh pe block ------
// Wave-per-row: 1024 blocks x 4 waves; f32x4 loads, shuffle-only reduce, uint4 kva store.
__global__ __launch_bounds__(256) void k_prep_latent(
    const float* __restrict__ latent, const float* __restrict__ w,
    const int* __restrict__ pos,
    unsigned short* __restrict__ kva, unsigned short* __restrict__ Kh) {
  int t = blockIdx.x * 4 + (threadIdx.x >> 6);
  int lane = threadIdx.x & 63;
  const float* row = latent + (size_t)t * (LKV + DROPE);
  f32x4 a = *(const f32x4*)&row[lane * 8];
  f32x4 b = *(const f32x4*)&row[lane * 8 + 4];
  float ss = a[0] * a[0] + a[1] * a[1] + a[2] * a[2] + a[3] * a[3] +
             b[0] * b[0] + b[1] * b[1] + b[2] * b[2] + b[3] * b[3];
  ss += __shfl_xor(ss, 1, 64);
  ss += __shfl_xor(ss, 2, 64);
  ss += __shfl_xor(ss, 4, 64);
  ss += __shfl_xor(ss, 8, 64);
  ss += __shfl_xor(ss, 16, 64);
  ss += __shfl_xor(ss, 32, 64);
  float rs = rsqrtf(ss / (float)LKV + 1e-6f);
  f32x4 w0 = *(const f32x4*)&w[lane * 8];
  f32x4 w1 = *(const f32x4*)&w[lane * 8 + 4];
  unsigned q0 = (unsigned)f2b(a[0] * rs * w0[0]) | ((unsigned)f2b(a[1] * rs * w0[1]) << 16);
  unsigned q1 = (unsigned)f2b(a[2] * rs * w0[2]) | ((unsigned)f2b(a[3] * rs * w0[3]) << 16);
  unsigned q2 = (unsigned)f2b(b[0] * rs * w1[0]) | ((unsigned)f2b(b[1] * rs * w1[1]) << 16);
  unsigned q3 = (unsigned)f2b(b[2] * rs * w1[2]) | ((unsigned)f2b(b[3] * rs * w1[3]) << 16);
  uint4 pk = {q0, q1, q2, q3};
  *(uint4*)&kva[(size_t)t * LKV + lane * 8] = pk;

  // k_pe rope: lane i handles rope element i (DROPE = 64 = wave size)
  int i = lane;
  float p = (float)pos[t];
  float val;
  if (i < 32) {
    float x1 = row[LKV + i], x2 = row[LKV + i + 32];
    float inv = __expf(-(float)i * 0.2878231366242557f);
    float sn, cs; __sincosf(p * inv, &sn, &cs);
    val = x1 * cs - x2 * sn;
  } else {
    float x1 = row[LKV + i - 32], x2 = row[LKV + i];
    float inv = __expf(-(float)(i - 32) * 0.2878231366242557f);
    float sn, cs; __sincosf(p * inv, &sn, &cs);
    val = x2 * cs + x1 * sn;
  }
  unsigned short vb = f2b(val);
#pragma unroll
  for (int h = 0; h < NH; h++)
    Kh[((size_t)h * T_LEN + t) * DQK + DNOPE + i] = vb;
}

// ---------------- fused flash attention v10 (best measured: 148.3us) ---------------------
// Dual q-set, same-CU complementary pairing, aligned streams, true async double-buffer
// with raw s_barrier. Split-k attempts broke L2 stream alignment and regressed; the
// 64-serial-tile makespan at ~5500cyc/step is this structure's floor. FROZEN.
__global__ __launch_bounds__(256, 2) void k_flash(
    const unsigned short* __restrict__ Qh, const unsigned short* __restrict__ Kh,
    const unsigned short* __restrict__ VT, unsigned short* __restrict__ attn) {
  int bx = blockIdx.x;
  int h = bx & 15;
  int t = (bx & 255) >> 4;                 // 0..15
  int qb = (bx < 256) ? (31 - t) : t;      // heavy half / light half (qb 16..31 / 0..15)
  int m0 = qb * 128;
  int diagA = 2 * qb, diagB = 2 * qb + 1;
  int NT = 2 * qb + 2;                     // tiles 0..diagB

  __shared__ unsigned short Ks[2 * 64 * 24 * 8];   // 48 KB (double-buffered)
  __shared__ unsigned short Vs[2 * 128 * 8 * 8];   // 32 KB (double-buffered)

  int tid = threadIdx.x, lane = tid & 63, w = tid >> 6;
  int quad = lane >> 4, l16 = lane & 15;
  int x = l16 & 7;

  const unsigned short* Qbase = Qh + (size_t)h * T_LEN * DQK;
  const unsigned short* Kbase = Kh + (size_t)h * T_LEN * DQK;
  const unsigned short* Vbase = VT + (size_t)h * DV * T_LEN;

  // Q fragments: set S = rows [m0, m0+64), set L = rows [m0+64, m0+128)
  bf16x8 qfS[6], qfL[6];
#pragma unroll
  for (int kk = 0; kk < 6; kk++) {
    qfS[kk] = *(const bf16x8*)(Qbase + (size_t)(m0 + w * 16 + l16) * DQK + kk * 32 + quad * 8);
    qfL[kk] = *(const bf16x8*)(Qbase + (size_t)(m0 + 64 + w * 16 + l16) * DQK + kk * 32 + quad * 8);
  }

  // staging source element-offsets (j-invariant bases; += per staged tile)
  int koff[6], voff[4];
#pragma unroll
  for (int k = 0; k < 6; k++) {
    int c = tid + k * 256;
    int row = c / 24, sc = c - row * 24;
    int cg = (sc & 0x18) | ((sc ^ row) & 7);
    koff[k] = row * DQK + cg * 8;
  }
#pragma unroll
  for (int k = 0; k < 4; k++) {
    int c = tid + k * 256;
    int row = c >> 3, sc = c & 7;
    int cg = sc ^ (row & 7);
    voff[k] = row * T_LEN + cg * 8;
  }

  // LDS read element-offsets WITHIN one buffer (j-invariant)
  int kEo[4], kOo[4], vAo[4];
#pragma unroll
  for (int st = 0; st < 4; st++) {
    int rb = (st * 16 + l16) * 192;                    // 24 chunks * 8 el per row
    kEo[st] = rb + ((quad ^ x) * 8);                   // kk even: cg&7 = quad
    kOo[st] = rb + (((quad + 4) ^ x) * 8);             // kk odd:  cg&7 = quad+4
    vAo[st] = l16 * 64 + (((st * 2 + (quad >> 1)) ^ x) * 8) + (quad & 1) * 4;
  }

  f32x4 OaccS[8] = {}, OaccL[8] = {};
  float liS = 0.f, liL = 0.f;
  int mS = m0 + w * 16 + l16;
  int mL = mS + 64;

#if !HAVE_MFMA16
  int lA = l16 + ((quad & 1) << 5);
  int lB = lA + 16;
  bool lowq = (quad < 2);
  int vFo[2];
#pragma unroll
  for (int u = 0; u < 2; u++)
    vFo[u] = l16 * 64 + (((u * 4 + quad) ^ x) * 8);
#endif

#define STAGE(buf)                                                                         \
  do {                                                                                     \
    unsigned short* ksd = Ks + (buf) * (64 * 24 * 8);                                      \
    unsigned short* vsd = Vs + (buf) * (128 * 8 * 8);                                      \
    _Pragma("unroll")                                                                      \
    for (int k = 0; k < 6; k++) GL2LDS16(Kbase + koff[k], &ksd[(tid + k * 256) * 8]);      \
    _Pragma("unroll")                                                                      \
    for (int k = 0; k < 4; k++) GL2LDS16(Vbase + voff[k], &vsd[(tid + k * 256) * 8]);      \
    _Pragma("unroll")                                                                      \
    for (int k = 0; k < 6; k++) koff[k] += BN * DQK;                                       \
    _Pragma("unroll")                                                                      \
    for (int k = 0; k < 4; k++) voff[k] += BN;                                             \
  } while (0)

// raw barrier: own loads drained (vmcnt), then block-sync, then fence the scheduler so
// no LDS access of the next phase is hoisted above the barrier (guide rule #18).
#define PIPE_BARRIER()                                                                     \
  do {                                                                                     \
    asm volatile("s_waitcnt vmcnt(0)" ::: "memory");                                       \
    __builtin_amdgcn_s_barrier();                                                          \
    __builtin_amdgcn_sched_barrier(0);                                                     \
  } while (0)

  // prologue: stage tile 0 into buffer 0, drain, sync
  STAGE(0);
  PIPE_BARRIER();

  int cur = 0;
  for (int j = 0; j < NT; ++j) {
    // issue next-tile prefetch into the other buffer (in flight across the compute)
    if (j + 1 < NT) STAGE(cur ^ 1);

    const unsigned short* KsB = Ks + cur * (64 * 24 * 8);
    const unsigned short* VsB = Vs + cur * (128 * 8 * 8);

    // S^T = K Q^T for both q-sets: C-layout col = m_q (l16), row = s (quad*4+r), per st
    f32x4 ScS[4] = {}, ScL[4] = {};
#pragma unroll
    for (int kk = 0; kk < 6; kk++) {
#pragma unroll
      for (int st = 0; st < 4; st++) {
        bf16x8 kb = *(const bf16x8*)(KsB + ((kk & 1) ? kOo[st] : kEo[st]) + (kk >> 1) * 64);
        ScS[st] = __builtin_amdgcn_mfma_f32_16x16x32_bf16(kb, qfS[kk], ScS[st], 0, 0, 0);
        ScL[st] = __builtin_amdgcn_mfma_f32_16x16x32_bf16(kb, qfL[kk], ScL[st], 0, 0, 0);
      }
    }

    // causal masks: set S diagonal at j==diagA (fully masked at j==diagB);
    // set L diagonal at j==diagB.
    int n0 = j * BN;
    if (j >= diagA) {
#pragma unroll
      for (int st = 0; st < 4; st++)
#pragma unroll
        for (int r = 0; r < 4; r++) {
          int s = n0 + st * 16 + quad * 4 + r;
          if (s > mS) ScS[st][r] = -1e30f;
        }
    }
    if (j == diagB) {
#pragma unroll
      for (int st = 0; st < 4; st++)
#pragma unroll
        for (int r = 0; r < 4; r++) {
          int s = n0 + st * 16 + quad * 4 + r;
          if (s > mL) ScL[st][r] = -1e30f;
        }
    }

    // exp + row-sum partials + pack to bf16 pairs (truncation via v_perm)
    unsigned p0S[4], p1S[4], p0L[4], p1L[4];
#pragma unroll
    for (int st = 0; st < 4; st++) {
      float e0 = __expf(ScS[st][0]);
      float e1 = __expf(ScS[st][1]);
      float e2 = __expf(ScS[st][2]);
      float e3 = __expf(ScS[st][3]);
      liS += (e0 + e1) + (e2 + e3);
      p0S[st] = __builtin_amdgcn_perm(__builtin_bit_cast(unsigned, e1),
                                      __builtin_bit_cast(unsigned, e0), 0x07060302u);
      p1S[st] = __builtin_amdgcn_perm(__builtin_bit_cast(unsigned, e3),
                                      __builtin_bit_cast(unsigned, e2), 0x07060302u);
      float f0 = __expf(ScL[st][0]);
      float f1 = __expf(ScL[st][1]);
      float f2 = __expf(ScL[st][2]);
      float f3 = __expf(ScL[st][3]);
      liL += (f0 + f1) + (f2 + f3);
      p0L[st] = __builtin_amdgcn_perm(__builtin_bit_cast(unsigned, f1),
                                      __builtin_bit_cast(unsigned, f0), 0x07060302u);
      p1L[st] = __builtin_amdgcn_perm(__builtin_bit_cast(unsigned, f3),
                                      __builtin_bit_cast(unsigned, f2), 0x07060302u);
    }

#if HAVE_MFMA16
    // O^T += V^T P^T with K=16 mfma; each V fragment read once, feeds both q-sets
#pragma unroll
    for (int st = 0; st < 4; st++) {
      uint2 puS; puS.x = p0S[st]; puS.y = p1S[st];
      s16x4 pbS = __builtin_bit_cast(s16x4, puS);
      uint2 puL; puL.x = p0L[st]; puL.y = p1L[st];
      s16x4 pbL = __builtin_bit_cast(s16x4, puL);
#pragma unroll
      for (int dt = 0; dt < 8; dt++) {
        s16x4 va = __builtin_bit_cast(s16x4, *(const uint2*)(VsB + vAo[st] + dt * 1024));
        OaccS[dt] = mfma16(va, pbS, OaccS[dt]);
        OaccL[dt] = mfma16(va, pbL, OaccL[dt]);
      }
    }
#else
    // fallback: bpermute transpose + K=32 PV (both sets)
#pragma unroll
    for (int u = 0; u < 2; u++) {
      int a0 = __shfl((int)p0S[2 * u], lA, 64);
      int a1 = __shfl((int)p0S[2 * u + 1], lA, 64);
      int b0 = __shfl((int)p1S[2 * u], lA, 64);
      int b1 = __shfl((int)p1S[2 * u + 1], lA, 64);
      int c0 = __shfl((int)p0S[2 * u], lB, 64);
      int c1 = __shfl((int)p0S[2 * u + 1], lB, 64);
      int d0 = __shfl((int)p1S[2 * u], lB, 64);
      int d1 = __shfl((int)p1S[2 * u + 1], lB, 64);
      int4 pkS;
      pkS.x = lowq ? a0 : a1; pkS.y = lowq ? b0 : b1;
      pkS.z = lowq ? c0 : c1; pkS.w = lowq ? d0 : d1;
      bf16x8 pbS = __builtin_bit_cast(bf16x8, pkS);
      int sa0 = __shfl((int)p0L[2 * u], lA, 64);
      int sa1 = __shfl((int)p0L[2 * u + 1], lA, 64);
      int sb0 = __shfl((int)p1L[2 * u], lA, 64);
      int sb1 = __shfl((int)p1L[2 * u + 1], lA, 64);
      int sc0 = __shfl((int)p0L[2 * u], lB, 64);
      int sc1 = __shfl((int)p0L[2 * u + 1], lB, 64);
      int sd0 = __shfl((int)p1L[2 * u], lB, 64);
      int sd1 = __shfl((int)p1L[2 * u + 1], lB, 64);
      int4 pkL;
      pkL.x = lowq ? sa0 : sa1; pkL.y = lowq ? sb0 : sb1;
      pkL.z = lowq ? sc0 : sc1; pkL.w = lowq ? sd0 : sd1;
      bf16x8 pbL = __builtin_bit_cast(bf16x8, pkL);
#pragma unroll
      for (int dt = 0; dt < 8; dt++) {
        bf16x8 va = *(const bf16x8*)(VsB + vFo[u] + dt * 1024);
        OaccS[dt] = __builtin_amdgcn_mfma_f32_16x16x32_bf16(va, pbS, OaccS[dt], 0, 0, 0);
        OaccL[dt] = __builtin_amdgcn_mfma_f32_16x16x32_bf16(va, pbL, OaccL[dt], 0, 0, 0);
      }
    }
#endif

    // single barrier per tile: own prefetch drained (cheap: it had ~full tile of
    // compute to land), then all waves done reading buf `cur` -> safe to overwrite.
    PIPE_BARRIER();
    cur ^= 1;
  }

  // reduce li across the 4 quads (each lane holds partial for its m_q = l16 column)
  liS += __shfl_xor(liS, 16, 64);
  liS += __shfl_xor(liS, 32, 64);
  liL += __shfl_xor(liL, 16, 64);
  liL += __shfl_xor(liL, 32, 64);

  // epilogue: attn[t][h*128 + d] = O^T[d][m_q] / li
  float invS = 1.f / liS;
  float invL = 1.f / liL;
  unsigned short* dstS = attn + (size_t)mS * HID_DIM + h * DV + quad * 4;
  unsigned short* dstL = attn + (size_t)mL * HID_DIM + h * DV + quad * 4;
#pragma unroll
  for (int dt = 0; dt < 8; dt++) {
    unsigned lo = (unsigned)f2b(OaccS[dt][0] * invS) |
                  ((unsigned)f2b(OaccS[dt][1] * invS) << 16);
    unsigned hi = (unsigned)f2b(OaccS[dt][2] * invS) |
                  ((unsigned)f2b(OaccS[dt][3] * invS) << 16);
    uint2 pkv = {lo, hi};
    *(uint2*)(dstS + dt * 16) = pkv;
    unsigned lo2 = (unsigned)f2b(OaccL[dt][0] * invL) |
                   ((unsigned)f2b(OaccL[dt][1] * invL) << 16);
    unsigned hi2 = (unsigned)f2b(OaccL[dt][2] * invL) |
                   ((unsigned)f2b(OaccL[dt][3] * invL) << 16);
    uint2 pkv2 = {lo2, hi2};
    *(uint2*)(dstL + dt * 16) = pkv2;
  }
#undef STAGE
#undef PIPE_BARRIER
}

extern "C" void kernel_launch(void* const* d_in, const int* in_sizes, int n_in,
                              void* d_out, int out_size, void* d_ws, size_t ws_size,
                              hipStream_t stream) {
  const int*   positions = (const int*)d_in[0];
  const float* hs   = (const float*)d_in[1];
  const float* Wq   = (const float*)d_in[2];
  const float* Wkva = (const float*)d_in[3];
  const float* lnw  = (const float*)d_in[4];
  const float* Wkvb = (const float*)d_in[5];
  const float* Wo   = (const float*)d_in[6];
  float* out = (float*)d_out;

  char* p = (char*)d_ws;
  size_t off = 0;
  auto alloc = [&](size_t bytes) {
    char* r = p + off;
    off = (off + bytes + 255) & ~(size_t)255;
    return r;
  };
  unsigned short* hsb     = (unsigned short*)alloc((size_t)T_LEN * HID_DIM * 2);
  unsigned short* WqT     = (unsigned short*)alloc((size_t)(NH * DQK) * HID_DIM * 2);
  unsigned short* WkvaT   = (unsigned short*)alloc((size_t)(LKV + DROPE) * HID_DIM * 2);
  unsigned short* WkvbT   = (unsigned short*)alloc((size_t)(NH * 256) * LKV * 2);
  unsigned short* WoT     = (unsigned short*)alloc((size_t)HID_DIM * HID_DIM * 2);
  unsigned short* Qh      = (unsigned short*)alloc((size_t)NH * T_LEN * DQK * 2);
  unsigned short* kva     = (unsigned short*)alloc((size_t)T_LEN * LKV * 2);
  unsigned short* Kh      = (unsigned short*)alloc((size_t)NH * T_LEN * DQK * 2);
  unsigned short* VT      = (unsigned short*)alloc((size_t)NH * DV * T_LEN * 2);
  unsigned short* attn    = (unsigned short*)alloc((size_t)T_LEN * HID_DIM * 2);
  float*          latentf = (float*)alloc((size_t)T_LEN * (LKV + DROPE) * 4);

  // --- stage 0: all weight transposes + fused hs cvt (one launch) ---
  k_transpose_all<<<17536, dim3(32, 8), 0, stream>>>(Wq, Wkva, Wkvb, Wo, hs,
                                                     WqT, WkvaT, WkvbT, WoT, hsb);

  // --- stage 1: merged Wq (rope fused) + Wkva projections (XCD-swizzled) ---
  k_gemm_proj<<<dim3(29, T_LEN / 128), 256, 0, stream>>>(hsb, WqT, WkvaT, positions, Qh, latentf);

  // --- stage 2: rmsnorm + k_pe rope prep (wave-per-row) ---
  k_prep_latent<<<T_LEN / 4, 256, 0, stream>>>(latentf, lnw, positions, kva, Kh);

  // --- stage 3: kv projection with fused scatter -> Kh nope / V^T (XCD-swizzled) ---
  k_gemm_wkvb<<<dim3((NH * 256) / 128, T_LEN / 128), 256, 0, stream>>>(kva, WkvbT, Kh, VT);

  // --- stage 4: fused flash attention (dual q-set, true async double-buffer) ---
  k_flash<<<dim3(512), 256, 0, stream>>>(Qh, Kh, VT, attn);

  // --- stage 5: out = attn @ Wo -> f32 (XCD-swizzled) ---
  k_gemm128<<<dim3(HID_DIM / 128, T_LEN / 128), 256, 0, stream>>>(
      attn, WoT, out, HID_DIM, HID_DIM, HID_DIM, HID_DIM, HID_DIM);
}

// Round 12
// 428.391 us; speedup vs baseline: 1.0832x; 1.0832x over previous
//
#include <hip/hip_runtime.h>
#include <hip/hip_bf16.h>

// Problem constants
#define T_LEN 4096
#define HID_DIM 2048
#define NH 16
#define DNOPE 128
#define DROPE 64
#define DV 128
#define LKV 512
#define DQK 192   // DNOPE + DROPE

#define BN 64     // flash k-tile width

typedef __attribute__((ext_vector_type(8))) __bf16 bf16x8;
typedef __attribute__((ext_vector_type(4))) float f32x4;
typedef __attribute__((ext_vector_type(4))) short s16x4;

__device__ __forceinline__ unsigned short f2b(float f) {
  unsigned u = __builtin_bit_cast(unsigned, f);
  unsigned r = (u + 0x7FFFu + ((u >> 16) & 1u)) >> 16;
  return (unsigned short)r;
}

#define GL2LDS16(gp, lp)                                                   \
  __builtin_amdgcn_global_load_lds(                                        \
      (const __attribute__((address_space(1))) unsigned int*)(gp),         \
      (__attribute__((address_space(3))) unsigned int*)(lp), 16, 0, 0)

// K=16 PV mfma: B-operand layout (n=l16, k=quad*4+j) == S^T C-layout -> zero transpose.
#if __has_builtin(__builtin_amdgcn_mfma_f32_16x16x16bf16_1k)
#define HAVE_MFMA16 1
__device__ __forceinline__ f32x4 mfma16(s16x4 a, s16x4 b, f32x4 c) {
  return __builtin_amdgcn_mfma_f32_16x16x16bf16_1k(a, b, c, 0, 0, 0);
}
#elif __has_builtin(__builtin_amdgcn_mfma_f32_16x16x16_bf16)
#define HAVE_MFMA16 1
typedef __attribute__((ext_vector_type(4))) __bf16 bf16x4v;
__device__ __forceinline__ f32x4 mfma16(s16x4 a, s16x4 b, f32x4 c) {
  return __builtin_amdgcn_mfma_f32_16x16x16_bf16(
      __builtin_bit_cast(bf16x4v, a), __builtin_bit_cast(bf16x4v, b), c, 0, 0, 0);
}
#else
#define HAVE_MFMA16 0
#endif

// XCD-aware bijective block swizzle (T1): consecutive linear ids chunk onto one XCD so
// blocks sharing A/B panels hit the same L2. Requires nwg % 8 == 0 (all our GEMM grids).
__device__ __forceinline__ void xcd_swz(int nbx, int* bx, int* by) {
  int lin = blockIdx.y * nbx + blockIdx.x;
  int cpx = (nbx * gridDim.y) >> 3;
  int swz = (lin & 7) * cpx + (lin >> 3);
  *bx = swz % nbx;
  *by = swz / nbx;
}

// ---------------- all 4 weight transposes + fused hs f32->bf16 cvt (one launch) ----------
// bid >= 13440: vectorized cvt of hidden_states. Transpose write side packs 4 output
// elements per thread into one 8B uint2 store.
__global__ void k_transpose_all(const float* __restrict__ Wq, const float* __restrict__ Wkva,
                                const float* __restrict__ Wkvb, const float* __restrict__ Wo,
                                const float* __restrict__ hs,
                                unsigned short* __restrict__ WqT, unsigned short* __restrict__ WkvaT,
                                unsigned short* __restrict__ WkvbT, unsigned short* __restrict__ WoT,
                                unsigned short* __restrict__ hsb) {
  int bid = blockIdx.x;
  int tx = threadIdx.x, ty = threadIdx.y;
  if (bid >= 13440) {
    int i = (bid - 13440) * 256 + ty * 32 + tx;   // thread index over 1,048,576
    const float4* in4 = (const float4*)hs;
    float4 v0 = in4[i * 2];
    float4 v1 = in4[i * 2 + 1];
    unsigned a = (unsigned)f2b(v0.x) | ((unsigned)f2b(v0.y) << 16);
    unsigned b = (unsigned)f2b(v0.z) | ((unsigned)f2b(v0.w) << 16);
    unsigned c = (unsigned)f2b(v1.x) | ((unsigned)f2b(v1.y) << 16);
    unsigned d = (unsigned)f2b(v1.z) | ((unsigned)f2b(v1.w) << 16);
    uint4 pk = {a, b, c, d};
    ((uint4*)hsb)[i] = pk;
    return;
  }
  __shared__ float t[32][33];
  const float* in; unsigned short* out; int R, C, bx, by;
  if (bid < 6144)      { in = Wq;   out = WqT;   R = 2048; C = 3072; bx = bid % 96;  by = bid / 96; }
  else if (bid < 7296) { int b = bid - 6144; in = Wkva; out = WkvaT; R = 2048; C = 576;  bx = b % 18;  by = b / 18; }
  else if (bid < 9344) { int b = bid - 7296; in = Wkvb; out = WkvbT; R = 512;  C = 4096; bx = b % 128; by = b / 128; }
  else                 { int b = bid - 9344; in = Wo;   out = WoT;   R = 2048; C = 2048; bx = b % 64;  by = b / 64; }
  int c0 = bx * 32, r0 = by * 32;
#pragma unroll
  for (int k = 0; k < 4; k++)
    t[ty + 8 * k][tx] = in[(size_t)(r0 + ty + 8 * k) * C + c0 + tx];
  __syncthreads();
  int u = ty * 32 + tx;
  int co = u >> 3;          // 0..31: column within tile (= output row c0+co)
  int rg = u & 7;           // 0..7:  group of 4 output cols (= input rows r0+rg*4..+3)
  unsigned lo = (unsigned)f2b(t[rg * 4 + 0][co]) | ((unsigned)f2b(t[rg * 4 + 1][co]) << 16);
  unsigned hi = (unsigned)f2b(t[rg * 4 + 2][co]) | ((unsigned)f2b(t[rg * 4 + 3][co]) << 16);
  uint2 pk = {lo, hi};
  *(uint2*)&out[(size_t)(c0 + co) * R + r0 + rg * 4] = pk;
}

// ------------- 128x128 LDS-staged MFMA GEMM core, BK=64 (R12) ----------------------------
// R12: BK 32 -> 64. Mechanism (m233): 2-phase overhead = per-step stage-drain + barrier
// (fixed ~300-500cyc each); halving K-step count halves those events. LDS 2x16KB -> 2x32KB
// keeps ~4-5 blocks/CU (m132's BK=128 regression needed 64KB/2-blocks). Fragment reads at
// 128B row stride would be 16-way bank-conflicted, so staging uses the XOR swizzle proven
// in k_flash: source col-group cg = sc ^ (row&7), linear LDS dest (gl2lds-compatible),
// read at ((ks*4+quad) ^ (row&7)) -> banks distinct across 8-row stripes (conflict-free).
#define GEMM_CORE(Aptr, Btptr, Nn, Kk, ldaa, ldbb)                                         \
  __shared__ unsigned short As[128 * 64];                                                  \
  __shared__ unsigned short Bs[128 * 64];                                                  \
  int tid = threadIdx.x;                                                                   \
  int lane = tid & 63, w = tid >> 6;                                                       \
  int quad = lane >> 4, l16 = lane & 15;                                                   \
  int wm = (w >> 1) * 64, wn = (w & 1) * 64;                                               \
  size_t aoff[4], boff[4];                                                                 \
  _Pragma("unroll")                                                                        \
  for (int k = 0; k < 4; k++) {                                                            \
    int c = tid + k * 256;                                                                 \
    int row = c >> 3, sc = c & 7;                                                          \
    int cg = sc ^ (row & 7);                                                               \
    aoff[k] = (size_t)(m0 + row) * (ldaa) + cg * 8;                                        \
    int bR = n0 + row; if (bR >= (Nn)) bR = (Nn) - 1;                                      \
    boff[k] = (size_t)bR * (ldbb) + cg * 8;                                                \
  }                                                                                        \
  f32x4 acc[4][4] = {};                                                                    \
  for (int k0 = 0; k0 < (Kk); k0 += 64) {                                                  \
    _Pragma("unroll")                                                                      \
    for (int k = 0; k < 4; k++) {                                                          \
      GL2LDS16((Aptr) + aoff[k] + k0, &As[(tid + k * 256) * 8]);                           \
      GL2LDS16((Btptr) + boff[k] + k0, &Bs[(tid + k * 256) * 8]);                          \
    }                                                                                      \
    __syncthreads();                                                                       \
    _Pragma("unroll")                                                                      \
    for (int ks = 0; ks < 2; ks++) {                                                       \
      bf16x8 aF[4], bF[4];                                                                 \
      _Pragma("unroll")                                                                    \
      for (int i = 0; i < 4; i++) {                                                        \
        int rowa = wm + i * 16 + l16;                                                      \
        aF[i] = *(const bf16x8*)&As[rowa * 64 + (((ks * 4 + quad) ^ (rowa & 7)) * 8)];     \
      }                                                                                    \
      _Pragma("unroll")                                                                    \
      for (int j = 0; j < 4; j++) {                                                        \
        int rowb = wn + j * 16 + l16;                                                      \
        bF[j] = *(const bf16x8*)&Bs[rowb * 64 + (((ks * 4 + quad) ^ (rowb & 7)) * 8)];     \
      }                                                                                    \
      _Pragma("unroll")                                                                    \
      for (int i = 0; i < 4; i++)                                                          \
        _Pragma("unroll")                                                                  \
        for (int j = 0; j < 4; j++)                                                        \
          acc[i][j] = __builtin_amdgcn_mfma_f32_16x16x32_bf16(aF[i], bF[j], acc[i][j], 0, 0, 0); \
    }                                                                                      \
    __syncthreads();                                                                       \
  }                                                                                        \
  int row0 = m0 + wm + quad * 4; (void)row0;

// ---------------- plain GEMM -> f32 C ----------------------------------------------------
__global__ __launch_bounds__(256) void k_gemm128(
    const unsigned short* __restrict__ A, const unsigned short* __restrict__ Bt,
    float* __restrict__ Cf, int N, int K, int lda, int ldb, int ldc) {
  int bxs, bys; xcd_swz(gridDim.x, &bxs, &bys);
  int m0 = bys * 128, n0 = bxs * 128;
  GEMM_CORE(A, Bt, N, K, lda, ldb)
#pragma unroll
  for (int i = 0; i < 4; i++)
#pragma unroll
    for (int j = 0; j < 4; j++) {
      int col = n0 + wn + j * 16 + l16;
      if (col < N)
#pragma unroll
        for (int r = 0; r < 4; r++)
          Cf[(size_t)(row0 + i * 16 + r) * ldc + col] = acc[i][j][r];
    }
}

// ---------------- merged Wq + Wkva projection (one launch, 29x32 grid) -------------------
// bx < 24: Wq tile with fused rope+scale -> Qh; bx >= 24: Wkva tile -> latentf f32.
__global__ __launch_bounds__(256) void k_gemm_proj(
    const unsigned short* __restrict__ A, const unsigned short* __restrict__ WqT,
    const unsigned short* __restrict__ WkvaT, const int* __restrict__ pos,
    unsigned short* __restrict__ Qh, float* __restrict__ latentf) {
  int bxx, byy; xcd_swz(gridDim.x, &bxx, &byy);
  bool iswq = bxx < 24;
  const unsigned short* Bt = iswq ? WqT : WkvaT;
  int N = iswq ? NH * DQK : (LKV + DROPE);
  int m0 = byy * 128, n0 = (iswq ? bxx : bxx - 24) * 128;
  GEMM_CORE(A, Bt, N, HID_DIM, HID_DIM, HID_DIM)
  if (iswq) {
    const float scale = 0.07216878364870323f;  // 1/sqrt(192)
    int b64 = (n0 + wn) >> 6;
    int h = b64 / 3, rem3 = b64 - 3 * h;
    unsigned short* Qb = Qh + (size_t)h * T_LEN * DQK;
    if (rem3 < 2) {
#pragma unroll
      for (int i = 0; i < 4; i++)
#pragma unroll
        for (int r = 0; r < 4; r++) {
          int t = row0 + i * 16 + r;
#pragma unroll
          for (int j = 0; j < 4; j++)
            Qb[(size_t)t * DQK + rem3 * 64 + j * 16 + l16] = f2b(acc[i][j][r] * scale);
        }
    } else {
      // rope branch: inv depends only on lane (idx = j*16+l16) -> hoist out of i/r loops
      float inv0 = __expf((float)l16 * -0.2878231366242557f);          // j=0
      float inv1 = __expf((float)(16 + l16) * -0.2878231366242557f);   // j=1
#pragma unroll
      for (int i = 0; i < 4; i++)
#pragma unroll
        for (int r = 0; r < 4; r++) {
          int t = row0 + i * 16 + r;
          float p = (float)pos[t];
#pragma unroll
          for (int j = 0; j < 2; j++) {
            int idx = j * 16 + l16;
            float inv = (j == 0) ? inv0 : inv1;
            float sn, cs;
            __sincosf(p * inv, &sn, &cs);
            float x1 = acc[i][j][r] * scale, x2 = acc[i][j + 2][r] * scale;
            Qb[(size_t)t * DQK + DNOPE + idx]      = f2b(x1 * cs - x2 * sn);
            Qb[(size_t)t * DQK + DNOPE + 32 + idx] = f2b(x2 * cs + x1 * sn);
          }
        }
    }
  } else {
#pragma unroll
    for (int i = 0; i < 4; i++)
#pragma unroll
      for (int j = 0; j < 4; j++) {
        int col = n0 + wn + j * 16 + l16;
        if (col < LKV + DROPE)
#pragma unroll
          for (int r = 0; r < 4; r++)
            latentf[(size_t)(row0 + i * 16 + r) * (LKV + DROPE) + col] = acc[i][j][r];
      }
  }
}

// ---------------- Wkvb GEMM with fused scatter -> Kh nope / V^T --------------------------
// VT epilogue packs the 4 t-consecutive values into one 8B uint2 store (t0 is 4-aligned).
// The c<128 branch is wave-uniform: c-runs are 16-aligned and never straddle 128.
__global__ __launch_bounds__(256) void k_gemm_wkvb(
    const unsigned short* __restrict__ A, const unsigned short* __restrict__ Bt,
    unsigned short* __restrict__ Kh, unsigned short* __restrict__ VT) {
  int bxs, bys; xcd_swz(gridDim.x, &bxs, &bys);
  int m0 = bys * 128, n0 = bxs * 128;
  GEMM_CORE(A, Bt, NH * 256, LKV, LKV, LKV)
#pragma unroll
  for (int i = 0; i < 4; i++)
#pragma unroll
    for (int j = 0; j < 4; j++) {
      int col = n0 + wn + j * 16 + l16;
      int h = col >> 8, c = col & 255;
      int t0 = row0 + i * 16;
      if (c < 128) {
#pragma unroll
        for (int r = 0; r < 4; r++)
          Kh[((size_t)h * T_LEN + t0 + r) * DQK + c] = f2b(acc[i][j][r]);
      } else {
        unsigned lo = (unsigned)f2b(acc[i][j][0]) | ((unsigned)f2b(acc[i][j][1]) << 16);
        unsigned hi = (unsigned)f2b(acc[i][j][2]) | ((unsigned)f2b(acc[i][j][3]) << 16);
        uint2 pk = {lo, hi};
        *(uint2*)&VT[(size_t)(h * 128 + c - 128) * T_LEN + t0] = pk;
      }
    }
}

// ---------------- latent f32 [T][576] -> kv_a bf16 [T][512] (rmsnorm) + Kh pe block ------
// Wave-per-row: 1024 blocks x 4 waves; f32x4 loads, shuffle-only reduce, uint4 kva store.
__global__ __launch_bounds__(256) void k_prep_latent(
    const float* __restrict__ latent, const float* __restrict__ w,
    const int* __restrict__ pos,
    unsigned short* __restrict__ kva, unsigned short* __restrict__ Kh) {
  int t = blockIdx.x * 4 + (threadIdx.x >> 6);
  int lane = threadIdx.x & 63;
  const float* row = latent + (size_t)t * (LKV + DROPE);
  f32x4 a = *(const f32x4*)&row[lane * 8];
  f32x4 b = *(const f32x4*)&row[lane * 8 + 4];
  float ss = a[0] * a[0] + a[1] * a[1] + a[2] * a[2] + a[3] * a[3] +
             b[0] * b[0] + b[1] * b[1] + b[2] * b[2] + b[3] * b[3];
  ss += __shfl_xor(ss, 1, 64);
  ss += __shfl_xor(ss, 2, 64);
  ss += __shfl_xor(ss, 4, 64);
  ss += __shfl_xor(ss, 8, 64);
  ss += __shfl_xor(ss, 16, 64);
  ss += __shfl_xor(ss, 32, 64);
  float rs = rsqrtf(ss / (float)LKV + 1e-6f);
  f32x4 w0 = *(const f32x4*)&w[lane * 8];
  f32x4 w1 = *(const f32x4*)&w[lane * 8 + 4];
  unsigned q0 = (unsigned)f2b(a[0] * rs * w0[0]) | ((unsigned)f2b(a[1] * rs * w0[1]) << 16);
  unsigned q1 = (unsigned)f2b(a[2] * rs * w0[2]) | ((unsigned)f2b(a[3] * rs * w0[3]) << 16);
  unsigned q2 = (unsigned)f2b(b[0] * rs * w1[0]) | ((unsigned)f2b(b[1] * rs * w1[1]) << 16);
  unsigned q3 = (unsigned)f2b(b[2] * rs * w1[2]) | ((unsigned)f2b(b[3] * rs * w1[3]) << 16);
  uint4 pk = {q0, q1, q2, q3};
  *(uint4*)&kva[(size_t)t * LKV + lane * 8] = pk;

  // k_pe rope: lane i handles rope element i (DROPE = 64 = wave size)
  int i = lane;
  float p = (float)pos[t];
  float val;
  if (i < 32) {
    float x1 = row[LKV + i], x2 = row[LKV + i + 32];
    float inv = __expf(-(float)i * 0.2878231366242557f);
    float sn, cs; __sincosf(p * inv, &sn, &cs);
    val = x1 * cs - x2 * sn;
  } else {
    float x1 = row[LKV + i - 32], x2 = row[LKV + i];
    float inv = __expf(-(float)(i - 32) * 0.2878231366242557f);
    float sn, cs; __sincosf(p * inv, &sn, &cs);
    val = x2 * cs + x1 * sn;
  }
  unsigned short vb = f2b(val);
#pragma unroll
  for (int h = 0; h < NH; h++)
    Kh[((size_t)h * T_LEN + t) * DQK + DNOPE + i] = vb;
}

// ---------------- fused flash attention v10 (best measured: 148.3us) ---------------------
// Dual q-set, same-CU complementary pairing, aligned streams, true async double-buffer
// with raw s_barrier. Split-k attempts broke L2 stream alignment and regressed; the
// 64-serial-tile makespan at ~5500cyc/step is this structure's floor. FROZEN.
__global__ __launch_bounds__(256, 2) void k_flash(
    const unsigned short* __restrict__ Qh, const unsigned short* __restrict__ Kh,
    const unsigned short* __restrict__ VT, unsigned short* __restrict__ attn) {
  int bx = blockIdx.x;
  int h = bx & 15;
  int t = (bx & 255) >> 4;                 // 0..15
  int qb = (bx < 256) ? (31 - t) : t;      // heavy half / light half (qb 16..31 / 0..15)
  int m0 = qb * 128;
  int diagA = 2 * qb, diagB = 2 * qb + 1;
  int NT = 2 * qb + 2;                     // tiles 0..diagB

  __shared__ unsigned short Ks[2 * 64 * 24 * 8];   // 48 KB (double-buffered)
  __shared__ unsigned short Vs[2 * 128 * 8 * 8];   // 32 KB (double-buffered)

  int tid = threadIdx.x, lane = tid & 63, w = tid >> 6;
  int quad = lane >> 4, l16 = lane & 15;
  int x = l16 & 7;

  const unsigned short* Qbase = Qh + (size_t)h * T_LEN * DQK;
  const unsigned short* Kbase = Kh + (size_t)h * T_LEN * DQK;
  const unsigned short* Vbase = VT + (size_t)h * DV * T_LEN;

  // Q fragments: set S = rows [m0, m0+64), set L = rows [m0+64, m0+128)
  bf16x8 qfS[6], qfL[6];
#pragma unroll
  for (int kk = 0; kk < 6; kk++) {
    qfS[kk] = *(const bf16x8*)(Qbase + (size_t)(m0 + w * 16 + l16) * DQK + kk * 32 + quad * 8);
    qfL[kk] = *(const bf16x8*)(Qbase + (size_t)(m0 + 64 + w * 16 + l16) * DQK + kk * 32 + quad * 8);
  }

  // staging source element-offsets (j-invariant bases; += per staged tile)
  int koff[6], voff[4];
#pragma unroll
  for (int k = 0; k < 6; k++) {
    int c = tid + k * 256;
    int row = c / 24, sc = c - row * 24;
    int cg = (sc & 0x18) | ((sc ^ row) & 7);
    koff[k] = row * DQK + cg * 8;
  }
#pragma unroll
  for (int k = 0; k < 4; k++) {
    int c = tid + k * 256;
    int row = c >> 3, sc = c & 7;
    int cg = sc ^ (row & 7);
    voff[k] = row * T_LEN + cg * 8;
  }

  // LDS read element-offsets WITHIN one buffer (j-invariant)
  int kEo[4], kOo[4], vAo[4];
#pragma unroll
  for (int st = 0; st < 4; st++) {
    int rb = (st * 16 + l16) * 192;                    // 24 chunks * 8 el per row
    kEo[st] = rb + ((quad ^ x) * 8);                   // kk even: cg&7 = quad
    kOo[st] = rb + (((quad + 4) ^ x) * 8);             // kk odd:  cg&7 = quad+4
    vAo[st] = l16 * 64 + (((st * 2 + (quad >> 1)) ^ x) * 8) + (quad & 1) * 4;
  }

  f32x4 OaccS[8] = {}, OaccL[8] = {};
  float liS = 0.f, liL = 0.f;
  int mS = m0 + w * 16 + l16;
  int mL = mS + 64;

#if !HAVE_MFMA16
  int lA = l16 + ((quad & 1) << 5);
  int lB = lA + 16;
  bool lowq = (quad < 2);
  int vFo[2];
#pragma unroll
  for (int u = 0; u < 2; u++)
    vFo[u] = l16 * 64 + (((u * 4 + quad) ^ x) * 8);
#endif

#define STAGE(buf)                                                                         \
  do {                                                                                     \
    unsigned short* ksd = Ks + (buf) * (64 * 24 * 8);                                      \
    unsigned short* vsd = Vs + (buf) * (128 * 8 * 8);                                      \
    _Pragma("unroll")                                                                      \
    for (int k = 0; k < 6; k++) GL2LDS16(Kbase + koff[k], &ksd[(tid + k * 256) * 8]);      \
    _Pragma("unroll")                                                                      \
    for (int k = 0; k < 4; k++) GL2LDS16(Vbase + voff[k], &vsd[(tid + k * 256) * 8]);      \
    _Pragma("unroll")                                                                      \
    for (int k = 0; k < 6; k++) koff[k] += BN * DQK;                                       \
    _Pragma("unroll")                                                                      \
    for (int k = 0; k < 4; k++) voff[k] += BN;                                             \
  } while (0)

// raw barrier: own loads drained (vmcnt), then block-sync, then fence the scheduler so
// no LDS access of the next phase is hoisted above the barrier (guide rule #18).
#define PIPE_BARRIER()                                                                     \
  do {                                                                                     \
    asm volatile("s_waitcnt vmcnt(0)" ::: "memory");                                       \
    __builtin_amdgcn_s_barrier();                                                          \
    __builtin_amdgcn_sched_barrier(0);                                                     \
  } while (0)

  // prologue: stage tile 0 into buffer 0, drain, sync
  STAGE(0);
  PIPE_BARRIER();

  int cur = 0;
  for (int j = 0; j < NT; ++j) {
    // issue next-tile prefetch into the other buffer (in flight across the compute)
    if (j + 1 < NT) STAGE(cur ^ 1);

    const unsigned short* KsB = Ks + cur * (64 * 24 * 8);
    const unsigned short* VsB = Vs + cur * (128 * 8 * 8);

    // S^T = K Q^T for both q-sets: C-layout col = m_q (l16), row = s (quad*4+r), per st
    f32x4 ScS[4] = {}, ScL[4] = {};
#pragma unroll
    for (int kk = 0; kk < 6; kk++) {
#pragma unroll
      for (int st = 0; st < 4; st++) {
        bf16x8 kb = *(const bf16x8*)(KsB + ((kk & 1) ? kOo[st] : kEo[st]) + (kk >> 1) * 64);
        ScS[st] = __builtin_amdgcn_mfma_f32_16x16x32_bf16(kb, qfS[kk], ScS[st], 0, 0, 0);
        ScL[st] = __builtin_amdgcn_mfma_f32_16x16x32_bf16(kb, qfL[kk], ScL[st], 0, 0, 0);
      }
    }

    // causal masks: set S diagonal at j==diagA (fully masked at j==diagB);
    // set L diagonal at j==diagB.
    int n0 = j * BN;
    if (j >= diagA) {
#pragma unroll
      for (int st = 0; st < 4; st++)
#pragma unroll
        for (int r = 0; r < 4; r++) {
          int s = n0 + st * 16 + quad * 4 + r;
          if (s > mS) ScS[st][r] = -1e30f;
        }
    }
    if (j == diagB) {
#pragma unroll
      for (int st = 0; st < 4; st++)
#pragma unroll
        for (int r = 0; r < 4; r++) {
          int s = n0 + st * 16 + quad * 4 + r;
          if (s > mL) ScL[st][r] = -1e30f;
        }
    }

    // exp + row-sum partials + pack to bf16 pairs (truncation via v_perm)
    unsigned p0S[4], p1S[4], p0L[4], p1L[4];
#pragma unroll
    for (int st = 0; st < 4; st++) {
      float e0 = __expf(ScS[st][0]);
      float e1 = __expf(ScS[st][1]);
      float e2 = __expf(ScS[st][2]);
      float e3 = __expf(ScS[st][3]);
      liS += (e0 + e1) + (e2 + e3);
      p0S[st] = __builtin_amdgcn_perm(__builtin_bit_cast(unsigned, e1),
                                      __builtin_bit_cast(unsigned, e0), 0x07060302u);
      p1S[st] = __builtin_amdgcn_perm(__builtin_bit_cast(unsigned, e3),
                                      __builtin_bit_cast(unsigned, e2), 0x07060302u);
      float f0 = __expf(ScL[st][0]);
      float f1 = __expf(ScL[st][1]);
      float f2 = __expf(ScL[st][2]);
      float f3 = __expf(ScL[st][3]);
      liL += (f0 + f1) + (f2 + f3);
      p0L[st] = __builtin_amdgcn_perm(__builtin_bit_cast(unsigned, f1),
                                      __builtin_bit_cast(unsigned, f0), 0x07060302u);
      p1L[st] = __builtin_amdgcn_perm(__builtin_bit_cast(unsigned, f3),
                                      __builtin_bit_cast(unsigned, f2), 0x07060302u);
    }

#if HAVE_MFMA16
    // O^T += V^T P^T with K=16 mfma; each V fragment read once, feeds both q-sets
#pragma unroll
    for (int st = 0; st < 4; st++) {
      uint2 puS; puS.x = p0S[st]; puS.y = p1S[st];
      s16x4 pbS = __builtin_bit_cast(s16x4, puS);
      uint2 puL; puL.x = p0L[st]; puL.y = p1L[st];
      s16x4 pbL = __builtin_bit_cast(s16x4, puL);
#pragma unroll
      for (int dt = 0; dt < 8; dt++) {
        s16x4 va = __builtin_bit_cast(s16x4, *(const uint2*)(VsB + vAo[st] + dt * 1024));
        OaccS[dt] = mfma16(va, pbS, OaccS[dt]);
        OaccL[dt] = mfma16(va, pbL, OaccL[dt]);
      }
    }
#else
    // fallback: bpermute transpose + K=32 PV (both sets)
#pragma unroll
    for (int u = 0; u < 2; u++) {
      int a0 = __shfl((int)p0S[2 * u], lA, 64);
      int a1 = __shfl((int)p0S[2 * u + 1], lA, 64);
      int b0 = __shfl((int)p1S[2 * u], lA, 64);
      int b1 = __shfl((int)p1S[2 * u + 1], lA, 64);
      int c0 = __shfl((int)p0S[2 * u], lB, 64);
      int c1 = __shfl((int)p0S[2 * u + 1], lB, 64);
      int d0 = __shfl((int)p1S[2 * u], lB, 64);
      int d1 = __shfl((int)p1S[2 * u + 1], lB, 64);
      int4 pkS;
      pkS.x = lowq ? a0 : a1; pkS.y = lowq ? b0 : b1;
      pkS.z = lowq ? c0 : c1; pkS.w = lowq ? d0 : d1;
      bf16x8 pbS = __builtin_bit_cast(bf16x8, pkS);
      int sa0 = __shfl((int)p0L[2 * u], lA, 64);
      int sa1 = __shfl((int)p0L[2 * u + 1], lA, 64);
      int sb0 = __shfl((int)p1L[2 * u], lA, 64);
      int sb1 = __shfl((int)p1L[2 * u + 1], lA, 64);
      int sc0 = __shfl((int)p0L[2 * u], lB, 64);
      int sc1 = __shfl((int)p0L[2 * u + 1], lB, 64);
      int sd0 = __shfl((int)p1L[2 * u], lB, 64);
      int sd1 = __shfl((int)p1L[2 * u + 1], lB, 64);
      int4 pkL;
      pkL.x = lowq ? sa0 : sa1; pkL.y = lowq ? sb0 : sb1;
      pkL.z = lowq ? sc0 : sc1; pkL.w = lowq ? sd0 : sd1;
      bf16x8 pbL = __builtin_bit_cast(bf16x8, pkL);
#pragma unroll
      for (int dt = 0; dt < 8; dt++) {
        bf16x8 va = *(const bf16x8*)(VsB + vFo[u] + dt * 1024);
        OaccS[dt] = __builtin_amdgcn_mfma_f32_16x16x32_bf16(va, pbS, OaccS[dt], 0, 0, 0);
        OaccL[dt] = __builtin_amdgcn_mfma_f32_16x16x32_bf16(va, pbL, OaccL[dt], 0, 0, 0);
      }
    }
#endif

    // single barrier per tile: own prefetch drained (cheap: it had ~full tile of
    // compute to land), then all waves done reading buf `cur` -> safe to overwrite.
    PIPE_BARRIER();
    cur ^= 1;
  }

  // reduce li across the 4 quads (each lane holds partial for its m_q = l16 column)
  liS += __shfl_xor(liS, 16, 64);
  liS += __shfl_xor(liS, 32, 64);
  liL += __shfl_xor(liL, 16, 64);
  liL += __shfl_xor(liL, 32, 64);

  // epilogue: attn[t][h*128 + d] = O^T[d][m_q] / li
  float invS = 1.f / liS;
  float invL = 1.f / liL;
  unsigned short* dstS = attn + (size_t)mS * HID_DIM + h * DV + quad * 4;
  unsigned short* dstL = attn + (size_t)mL * HID_DIM + h * DV + quad * 4;
#pragma unroll
  for (int dt = 0; dt < 8; dt++) {
    unsigned lo = (unsigned)f2b(OaccS[dt][0] * invS) |
                  ((unsigned)f2b(OaccS[dt][1] * invS) << 16);
    unsigned hi = (unsigned)f2b(OaccS[dt][2] * invS) |
                  ((unsigned)f2b(OaccS[dt][3] * invS) << 16);
    uint2 pkv = {lo, hi};
    *(uint2*)(dstS + dt * 16) = pkv;
    unsigned lo2 = (unsigned)f2b(OaccL[dt][0] * invL) |
                   ((unsigned)f2b(OaccL[dt][1] * invL) << 16);
    unsigned hi2 = (unsigned)f2b(OaccL[dt][2] * invL) |
                   ((unsigned)f2b(OaccL[dt][3] * invL) << 16);
    uint2 pkv2 = {lo2, hi2};
    *(uint2*)(dstL + dt * 16) = pkv2;
  }
#undef STAGE
#undef PIPE_BARRIER
}

extern "C" void kernel_launch(void* const* d_in, const int* in_sizes, int n_in,
                              void* d_out, int out_size, void* d_ws, size_t ws_size,
                              hipStream_t stream) {
  const int*   positions = (const int*)d_in[0];
  const float* hs   = (const float*)d_in[1];
  const float* Wq   = (const float*)d_in[2];
  const float* Wkva = (const float*)d_in[3];
  const float* lnw  = (const float*)d_in[4];
  const float* Wkvb = (const float*)d_in[5];
  const float* Wo   = (const float*)d_in[6];
  float* out = (float*)d_out;

  char* p = (char*)d_ws;
  size_t off = 0;
  auto alloc = [&](size_t bytes) {
    char* r = p + off;
    off = (off + bytes + 255) & ~(size_t)255;
    return r;
  };
  unsigned short* hsb     = (unsigned short*)alloc((size_t)T_LEN * HID_DIM * 2);
  unsigned short* WqT     = (unsigned short*)alloc((size_t)(NH * DQK) * HID_DIM * 2);
  unsigned short* WkvaT   = (unsigned short*)alloc((size_t)(LKV + DROPE) * HID_DIM * 2);
  unsigned short* WkvbT   = (unsigned short*)alloc((size_t)(NH * 256) * LKV * 2);
  unsigned short* WoT     = (unsigned short*)alloc((size_t)HID_DIM * HID_DIM * 2);
  unsigned short* Qh      = (unsigned short*)alloc((size_t)NH * T_LEN * DQK * 2);
  unsigned short* kva     = (unsigned short*)alloc((size_t)T_LEN * LKV * 2);
  unsigned short* Kh      = (unsigned short*)alloc((size_t)NH * T_LEN * DQK * 2);
  unsigned short* VT      = (unsigned short*)alloc((size_t)NH * DV * T_LEN * 2);
  unsigned short* attn    = (unsigned short*)alloc((size_t)T_LEN * HID_DIM * 2);
  float*          latentf = (float*)alloc((size_t)T_LEN * (LKV + DROPE) * 4);

  // --- stage 0: all weight transposes + fused hs cvt (one launch) ---
  k_transpose_all<<<17536, dim3(32, 8), 0, stream>>>(Wq, Wkva, Wkvb, Wo, hs,
                                                     WqT, WkvaT, WkvbT, WoT, hsb);

  // --- stage 1: merged Wq (rope fused) + Wkva projections (XCD-swizzled, BK=64) ---
  k_gemm_proj<<<dim3(29, T_LEN / 128), 256, 0, stream>>>(hsb, WqT, WkvaT, positions, Qh, latentf);

  // --- stage 2: rmsnorm + k_pe rope prep (wave-per-row) ---
  k_prep_latent<<<T_LEN / 4, 256, 0, stream>>>(latentf, lnw, positions, kva, Kh);

  // --- stage 3: kv projection with fused scatter -> Kh nope / V^T (XCD-swizzled, BK=64) ---
  k_gemm_wkvb<<<dim3((NH * 256) / 128, T_LEN / 128), 256, 0, stream>>>(kva, WkvbT, Kh, VT);

  // --- stage 4: fused flash attention (dual q-set, true async double-buffer) ---
  k_flash<<<dim3(512), 256, 0, stream>>>(Qh, Kh, VT, attn);

  // --- stage 5: out = attn @ Wo -> f32 (XCD-swizzled, BK=64) ---
  k_gemm128<<<dim3(HID_DIM / 128, T_LEN / 128), 256, 0, stream>>>(
      attn, WoT, out, HID_DIM, HID_DIM, HID_DIM, HID_DIM, HID_DIM);
}

// Round 13
// 415.152 us; speedup vs baseline: 1.1178x; 1.0319x over previous
//
#include <hip/hip_runtime.h>
#include <hip/hip_bf16.h>

// Problem constants
#define T_LEN 4096
#define HID_DIM 2048
#define NH 16
#define DNOPE 128
#define DROPE 64
#define DV 128
#define LKV 512
#define DQK 192   // DNOPE + DROPE

#define BN 64     // flash k-tile width

typedef __attribute__((ext_vector_type(8))) __bf16 bf16x8;
typedef __attribute__((ext_vector_type(4))) float f32x4;
typedef __attribute__((ext_vector_type(4))) short s16x4;

__device__ __forceinline__ unsigned short f2b(float f) {
  unsigned u = __builtin_bit_cast(unsigned, f);
  unsigned r = (u + 0x7FFFu + ((u >> 16) & 1u)) >> 16;
  return (unsigned short)r;
}

#define GL2LDS16(gp, lp)                                                   \
  __builtin_amdgcn_global_load_lds(                                        \
      (const __attribute__((address_space(1))) unsigned int*)(gp),         \
      (__attribute__((address_space(3))) unsigned int*)(lp), 16, 0, 0)

// K=16 PV mfma: B-operand layout (n=l16, k=quad*4+j) == S^T C-layout -> zero transpose.
#if __has_builtin(__builtin_amdgcn_mfma_f32_16x16x16bf16_1k)
#define HAVE_MFMA16 1
__device__ __forceinline__ f32x4 mfma16(s16x4 a, s16x4 b, f32x4 c) {
  return __builtin_amdgcn_mfma_f32_16x16x16bf16_1k(a, b, c, 0, 0, 0);
}
#elif __has_builtin(__builtin_amdgcn_mfma_f32_16x16x16_bf16)
#define HAVE_MFMA16 1
typedef __attribute__((ext_vector_type(4))) __bf16 bf16x4v;
__device__ __forceinline__ f32x4 mfma16(s16x4 a, s16x4 b, f32x4 c) {
  return __builtin_amdgcn_mfma_f32_16x16x16_bf16(
      __builtin_bit_cast(bf16x4v, a), __builtin_bit_cast(bf16x4v, b), c, 0, 0, 0);
}
#else
#define HAVE_MFMA16 0
#endif

// XCD-aware bijective block swizzle (T1): consecutive linear ids chunk onto one XCD so
// blocks sharing A/B panels hit the same L2. Requires nwg % 8 == 0 (all our GEMM grids).
__device__ __forceinline__ void xcd_swz(int nbx, int* bx, int* by) {
  int lin = blockIdx.y * nbx + blockIdx.x;
  int cpx = (nbx * gridDim.y) >> 3;
  int swz = (lin & 7) * cpx + (lin >> 3);
  *bx = swz % nbx;
  *by = swz / nbx;
}

// ---------------- all 4 weight transposes + fused hs f32->bf16 cvt (one launch) ----------
// bid >= 13440: vectorized cvt of hidden_states. Transpose write side packs 4 output
// elements per thread into one 8B uint2 store.
__global__ void k_transpose_all(const float* __restrict__ Wq, const float* __restrict__ Wkva,
                                const float* __restrict__ Wkvb, const float* __restrict__ Wo,
                                const float* __restrict__ hs,
                                unsigned short* __restrict__ WqT, unsigned short* __restrict__ WkvaT,
                                unsigned short* __restrict__ WkvbT, unsigned short* __restrict__ WoT,
                                unsigned short* __restrict__ hsb) {
  int bid = blockIdx.x;
  int tx = threadIdx.x, ty = threadIdx.y;
  if (bid >= 13440) {
    int i = (bid - 13440) * 256 + ty * 32 + tx;   // thread index over 1,048,576
    const float4* in4 = (const float4*)hs;
    float4 v0 = in4[i * 2];
    float4 v1 = in4[i * 2 + 1];
    unsigned a = (unsigned)f2b(v0.x) | ((unsigned)f2b(v0.y) << 16);
    unsigned b = (unsigned)f2b(v0.z) | ((unsigned)f2b(v0.w) << 16);
    unsigned c = (unsigned)f2b(v1.x) | ((unsigned)f2b(v1.y) << 16);
    unsigned d = (unsigned)f2b(v1.z) | ((unsigned)f2b(v1.w) << 16);
    uint4 pk = {a, b, c, d};
    ((uint4*)hsb)[i] = pk;
    return;
  }
  __shared__ float t[32][33];
  const float* in; unsigned short* out; int R, C, bx, by;
  if (bid < 6144)      { in = Wq;   out = WqT;   R = 2048; C = 3072; bx = bid % 96;  by = bid / 96; }
  else if (bid < 7296) { int b = bid - 6144; in = Wkva; out = WkvaT; R = 2048; C = 576;  bx = b % 18;  by = b / 18; }
  else if (bid < 9344) { int b = bid - 7296; in = Wkvb; out = WkvbT; R = 512;  C = 4096; bx = b % 128; by = b / 128; }
  else                 { int b = bid - 9344; in = Wo;   out = WoT;   R = 2048; C = 2048; bx = b % 64;  by = b / 64; }
  int c0 = bx * 32, r0 = by * 32;
#pragma unroll
  for (int k = 0; k < 4; k++)
    t[ty + 8 * k][tx] = in[(size_t)(r0 + ty + 8 * k) * C + c0 + tx];
  __syncthreads();
  int u = ty * 32 + tx;
  int co = u >> 3;          // 0..31: column within tile (= output row c0+co)
  int rg = u & 7;           // 0..7:  group of 4 output cols (= input rows r0+rg*4..+3)
  unsigned lo = (unsigned)f2b(t[rg * 4 + 0][co]) | ((unsigned)f2b(t[rg * 4 + 1][co]) << 16);
  unsigned hi = (unsigned)f2b(t[rg * 4 + 2][co]) | ((unsigned)f2b(t[rg * 4 + 3][co]) << 16);
  uint2 pk = {lo, hi};
  *(uint2*)&out[(size_t)(c0 + co) * R + r0 + rg * 4] = pk;
}

// ------------- 128x128 MFMA GEMM core, BK=64, async double-buffer (R13) ------------------
// R12 proved the GEMM stack is fixed-per-K-step-overhead-bound (BK 32->64 = -36us).
// R13 applies k_flash v10's proven pipeline to the same core: prefetch step k0+64 into
// buf^1, compute buf, then {vmcnt(0) drain (hidden behind 16 ds_reads + 32 MFMAs) +
// raw s_barrier + sched_barrier(0)}. One barrier per step (was 2), drain off the
// critical path. LDS 2x(16+16)KB = 64KB -> 2 blocks/CU (same co-residency as flash).
// Staging/read swizzle identical to R12 (refcheck-passed): src cg = sc^(row&7), linear
// LDS dest, read slot ((ks*4+quad)^(row&7)).
#define GBAR()                                                                             \
  do {                                                                                     \
    asm volatile("s_waitcnt vmcnt(0)" ::: "memory");                                       \
    __builtin_amdgcn_s_barrier();                                                          \
    __builtin_amdgcn_sched_barrier(0);                                                     \
  } while (0)

#define GEMM_STAGE(buf, kk0)                                                               \
  do {                                                                                     \
    _Pragma("unroll")                                                                      \
    for (int k = 0; k < 4; k++) {                                                          \
      GL2LDS16(APTR_ + aoff[k] + (kk0), &As[(buf) * 8192 + (tid + k * 256) * 8]);          \
      GL2LDS16(BPTR_ + boff[k] + (kk0), &Bs[(buf) * 8192 + (tid + k * 256) * 8]);          \
    }                                                                                      \
  } while (0)

#define GEMM_CORE(Aptr, Btptr, Nn, Kk, ldaa, ldbb)                                         \
  __shared__ unsigned short As[2 * 128 * 64];                                              \
  __shared__ unsigned short Bs[2 * 128 * 64];                                              \
  int tid = threadIdx.x;                                                                   \
  int lane = tid & 63, w = tid >> 6;                                                       \
  int quad = lane >> 4, l16 = lane & 15;                                                   \
  int wm = (w >> 1) * 64, wn = (w & 1) * 64;                                               \
  const unsigned short* APTR_ = (Aptr);                                                    \
  const unsigned short* BPTR_ = (Btptr);                                                   \
  size_t aoff[4], boff[4];                                                                 \
  _Pragma("unroll")                                                                        \
  for (int k = 0; k < 4; k++) {                                                            \
    int c = tid + k * 256;                                                                 \
    int row = c >> 3, sc = c & 7;                                                          \
    int cg = sc ^ (row & 7);                                                               \
    aoff[k] = (size_t)(m0 + row) * (ldaa) + cg * 8;                                        \
    int bR = n0 + row; if (bR >= (Nn)) bR = (Nn) - 1;                                      \
    boff[k] = (size_t)bR * (ldbb) + cg * 8;                                                \
  }                                                                                        \
  f32x4 acc[4][4] = {};                                                                    \
  GEMM_STAGE(0, 0);                                                                        \
  GBAR();                                                                                  \
  int cur = 0;                                                                             \
  for (int k0 = 0; k0 < (Kk); k0 += 64) {                                                  \
    if (k0 + 64 < (Kk)) GEMM_STAGE(cur ^ 1, k0 + 64);                                      \
    const unsigned short* AsB = As + cur * 8192;                                           \
    const unsigned short* BsB = Bs + cur * 8192;                                           \
    _Pragma("unroll")                                                                      \
    for (int ks = 0; ks < 2; ks++) {                                                       \
      bf16x8 aF[4], bF[4];                                                                 \
      _Pragma("unroll")                                                                    \
      for (int i = 0; i < 4; i++) {                                                        \
        int rowa = wm + i * 16 + l16;                                                      \
        aF[i] = *(const bf16x8*)&AsB[rowa * 64 + (((ks * 4 + quad) ^ (rowa & 7)) * 8)];    \
      }                                                                                    \
      _Pragma("unroll")                                                                    \
      for (int j = 0; j < 4; j++) {                                                        \
        int rowb = wn + j * 16 + l16;                                                      \
        bF[j] = *(const bf16x8*)&BsB[rowb * 64 + (((ks * 4 + quad) ^ (rowb & 7)) * 8)];    \
      }                                                                                    \
      _Pragma("unroll")                                                                    \
      for (int i = 0; i < 4; i++)                                                          \
        _Pragma("unroll")                                                                  \
        for (int j = 0; j < 4; j++)                                                        \
          acc[i][j] = __builtin_amdgcn_mfma_f32_16x16x32_bf16(aF[i], bF[j], acc[i][j], 0, 0, 0); \
    }                                                                                      \
    GBAR();                                                                                \
    cur ^= 1;                                                                              \
  }                                                                                        \
  int row0 = m0 + wm + quad * 4; (void)row0;

// ---------------- plain GEMM -> f32 C ----------------------------------------------------
__global__ __launch_bounds__(256, 2) void k_gemm128(
    const unsigned short* __restrict__ A, const unsigned short* __restrict__ Bt,
    float* __restrict__ Cf, int N, int K, int lda, int ldb, int ldc) {
  int bxs, bys; xcd_swz(gridDim.x, &bxs, &bys);
  int m0 = bys * 128, n0 = bxs * 128;
  GEMM_CORE(A, Bt, N, K, lda, ldb)
#pragma unroll
  for (int i = 0; i < 4; i++)
#pragma unroll
    for (int j = 0; j < 4; j++) {
      int col = n0 + wn + j * 16 + l16;
      if (col < N)
#pragma unroll
        for (int r = 0; r < 4; r++)
          Cf[(size_t)(row0 + i * 16 + r) * ldc + col] = acc[i][j][r];
    }
}

// ---------------- merged Wq + Wkva projection (one launch, 29x32 grid) -------------------
// bx < 24: Wq tile with fused rope+scale -> Qh; bx >= 24: Wkva tile -> latentf f32.
__global__ __launch_bounds__(256, 2) void k_gemm_proj(
    const unsigned short* __restrict__ A, const unsigned short* __restrict__ WqT,
    const unsigned short* __restrict__ WkvaT, const int* __restrict__ pos,
    unsigned short* __restrict__ Qh, float* __restrict__ latentf) {
  int bxx, byy; xcd_swz(gridDim.x, &bxx, &byy);
  bool iswq = bxx < 24;
  const unsigned short* Bt = iswq ? WqT : WkvaT;
  int N = iswq ? NH * DQK : (LKV + DROPE);
  int m0 = byy * 128, n0 = (iswq ? bxx : bxx - 24) * 128;
  GEMM_CORE(A, Bt, N, HID_DIM, HID_DIM, HID_DIM)
  if (iswq) {
    const float scale = 0.07216878364870323f;  // 1/sqrt(192)
    int b64 = (n0 + wn) >> 6;
    int h = b64 / 3, rem3 = b64 - 3 * h;
    unsigned short* Qb = Qh + (size_t)h * T_LEN * DQK;
    if (rem3 < 2) {
#pragma unroll
      for (int i = 0; i < 4; i++)
#pragma unroll
        for (int r = 0; r < 4; r++) {
          int t = row0 + i * 16 + r;
#pragma unroll
          for (int j = 0; j < 4; j++)
            Qb[(size_t)t * DQK + rem3 * 64 + j * 16 + l16] = f2b(acc[i][j][r] * scale);
        }
    } else {
      // rope branch: inv depends only on lane (idx = j*16+l16) -> hoist out of i/r loops
      float inv0 = __expf((float)l16 * -0.2878231366242557f);          // j=0
      float inv1 = __expf((float)(16 + l16) * -0.2878231366242557f);   // j=1
#pragma unroll
      for (int i = 0; i < 4; i++)
#pragma unroll
        for (int r = 0; r < 4; r++) {
          int t = row0 + i * 16 + r;
          float p = (float)pos[t];
#pragma unroll
          for (int j = 0; j < 2; j++) {
            int idx = j * 16 + l16;
            float inv = (j == 0) ? inv0 : inv1;
            float sn, cs;
            __sincosf(p * inv, &sn, &cs);
            float x1 = acc[i][j][r] * scale, x2 = acc[i][j + 2][r] * scale;
            Qb[(size_t)t * DQK + DNOPE + idx]      = f2b(x1 * cs - x2 * sn);
            Qb[(size_t)t * DQK + DNOPE + 32 + idx] = f2b(x2 * cs + x1 * sn);
          }
        }
    }
  } else {
#pragma unroll
    for (int i = 0; i < 4; i++)
#pragma unroll
      for (int j = 0; j < 4; j++) {
        int col = n0 + wn + j * 16 + l16;
        if (col < LKV + DROPE)
#pragma unroll
          for (int r = 0; r < 4; r++)
            latentf[(size_t)(row0 + i * 16 + r) * (LKV + DROPE) + col] = acc[i][j][r];
      }
  }
}

// ---------------- Wkvb GEMM with fused scatter -> Kh nope / V^T --------------------------
// VT epilogue packs the 4 t-consecutive values into one 8B uint2 store (t0 is 4-aligned).
// The c<128 branch is wave-uniform: c-runs are 16-aligned and never straddle 128.
__global__ __launch_bounds__(256, 2) void k_gemm_wkvb(
    const unsigned short* __restrict__ A, const unsigned short* __restrict__ Bt,
    unsigned short* __restrict__ Kh, unsigned short* __restrict__ VT) {
  int bxs, bys; xcd_swz(gridDim.x, &bxs, &bys);
  int m0 = bys * 128, n0 = bxs * 128;
  GEMM_CORE(A, Bt, NH * 256, LKV, LKV, LKV)
#pragma unroll
  for (int i = 0; i < 4; i++)
#pragma unroll
    for (int j = 0; j < 4; j++) {
      int col = n0 + wn + j * 16 + l16;
      int h = col >> 8, c = col & 255;
      int t0 = row0 + i * 16;
      if (c < 128) {
#pragma unroll
        for (int r = 0; r < 4; r++)
          Kh[((size_t)h * T_LEN + t0 + r) * DQK + c] = f2b(acc[i][j][r]);
      } else {
        unsigned lo = (unsigned)f2b(acc[i][j][0]) | ((unsigned)f2b(acc[i][j][1]) << 16);
        unsigned hi = (unsigned)f2b(acc[i][j][2]) | ((unsigned)f2b(acc[i][j][3]) << 16);
        uint2 pk = {lo, hi};
        *(uint2*)&VT[(size_t)(h * 128 + c - 128) * T_LEN + t0] = pk;
      }
    }
}

// ---------------- latent f32 [T][576] -> kv_a bf16 [T][512] (rmsnorm) + Kh pe block ------
// Wave-per-row: 1024 blocks x 4 waves; f32x4 loads, shuffle-only reduce, uint4 kva store.
__global__ __launch_bounds__(256) void k_prep_latent(
    const float* __restrict__ latent, const float* __restrict__ w,
    const int* __restrict__ pos,
    unsigned short* __restrict__ kva, unsigned short* __restrict__ Kh) {
  int t = blockIdx.x * 4 + (threadIdx.x >> 6);
  int lane = threadIdx.x & 63;
  const float* row = latent + (size_t)t * (LKV + DROPE);
  f32x4 a = *(const f32x4*)&row[lane * 8];
  f32x4 b = *(const f32x4*)&row[lane * 8 + 4];
  float ss = a[0] * a[0] + a[1] * a[1] + a[2] * a[2] + a[3] * a[3] +
             b[0] * b[0] + b[1] * b[1] + b[2] * b[2] + b[3] * b[3];
  ss += __shfl_xor(ss, 1, 64);
  ss += __shfl_xor(ss, 2, 64);
  ss += __shfl_xor(ss, 4, 64);
  ss += __shfl_xor(ss, 8, 64);
  ss += __shfl_xor(ss, 16, 64);
  ss += __shfl_xor(ss, 32, 64);
  float rs = rsqrtf(ss / (float)LKV + 1e-6f);
  f32x4 w0 = *(const f32x4*)&w[lane * 8];
  f32x4 w1 = *(const f32x4*)&w[lane * 8 + 4];
  unsigned q0 = (unsigned)f2b(a[0] * rs * w0[0]) | ((unsigned)f2b(a[1] * rs * w0[1]) << 16);
  unsigned q1 = (unsigned)f2b(a[2] * rs * w0[2]) | ((unsigned)f2b(a[3] * rs * w0[3]) << 16);
  unsigned q2 = (unsigned)f2b(b[0] * rs * w1[0]) | ((unsigned)f2b(b[1] * rs * w1[1]) << 16);
  unsigned q3 = (unsigned)f2b(b[2] * rs * w1[2]) | ((unsigned)f2b(b[3] * rs * w1[3]) << 16);
  uint4 pk = {q0, q1, q2, q3};
  *(uint4*)&kva[(size_t)t * LKV + lane * 8] = pk;

  // k_pe rope: lane i handles rope element i (DROPE = 64 = wave size)
  int i = lane;
  float p = (float)pos[t];
  float val;
  if (i < 32) {
    float x1 = row[LKV + i], x2 = row[LKV + i + 32];
    float inv = __expf(-(float)i * 0.2878231366242557f);
    float sn, cs; __sincosf(p * inv, &sn, &cs);
    val = x1 * cs - x2 * sn;
  } else {
    float x1 = row[LKV + i - 32], x2 = row[LKV + i];
    float inv = __expf(-(float)(i - 32) * 0.2878231366242557f);
    float sn, cs; __sincosf(p * inv, &sn, &cs);
    val = x2 * cs + x1 * sn;
  }
  unsigned short vb = f2b(val);
#pragma unroll
  for (int h = 0; h < NH; h++)
    Kh[((size_t)h * T_LEN + t) * DQK + DNOPE + i] = vb;
}

// ---------------- fused flash attention v10 (best measured: 148.3us) ---------------------
// Dual q-set, same-CU complementary pairing, aligned streams, true async double-buffer
// with raw s_barrier. Split-k attempts broke L2 stream alignment and regressed; the
// 64-serial-tile makespan at ~5500cyc/step is this structure's floor. FROZEN.
__global__ __launch_bounds__(256, 2) void k_flash(
    const unsigned short* __restrict__ Qh, const unsigned short* __restrict__ Kh,
    const unsigned short* __restrict__ VT, unsigned short* __restrict__ attn) {
  int bx = blockIdx.x;
  int h = bx & 15;
  int t = (bx & 255) >> 4;                 // 0..15
  int qb = (bx < 256) ? (31 - t) : t;      // heavy half / light half (qb 16..31 / 0..15)
  int m0 = qb * 128;
  int diagA = 2 * qb, diagB = 2 * qb + 1;
  int NT = 2 * qb + 2;                     // tiles 0..diagB

  __shared__ unsigned short Ks[2 * 64 * 24 * 8];   // 48 KB (double-buffered)
  __shared__ unsigned short Vs[2 * 128 * 8 * 8];   // 32 KB (double-buffered)

  int tid = threadIdx.x, lane = tid & 63, w = tid >> 6;
  int quad = lane >> 4, l16 = lane & 15;
  int x = l16 & 7;

  const unsigned short* Qbase = Qh + (size_t)h * T_LEN * DQK;
  const unsigned short* Kbase = Kh + (size_t)h * T_LEN * DQK;
  const unsigned short* Vbase = VT + (size_t)h * DV * T_LEN;

  // Q fragments: set S = rows [m0, m0+64), set L = rows [m0+64, m0+128)
  bf16x8 qfS[6], qfL[6];
#pragma unroll
  for (int kk = 0; kk < 6; kk++) {
    qfS[kk] = *(const bf16x8*)(Qbase + (size_t)(m0 + w * 16 + l16) * DQK + kk * 32 + quad * 8);
    qfL[kk] = *(const bf16x8*)(Qbase + (size_t)(m0 + 64 + w * 16 + l16) * DQK + kk * 32 + quad * 8);
  }

  // staging source element-offsets (j-invariant bases; += per staged tile)
  int koff[6], voff[4];
#pragma unroll
  for (int k = 0; k < 6; k++) {
    int c = tid + k * 256;
    int row = c / 24, sc = c - row * 24;
    int cg = (sc & 0x18) | ((sc ^ row) & 7);
    koff[k] = row * DQK + cg * 8;
  }
#pragma unroll
  for (int k = 0; k < 4; k++) {
    int c = tid + k * 256;
    int row = c >> 3, sc = c & 7;
    int cg = sc ^ (row & 7);
    voff[k] = row * T_LEN + cg * 8;
  }

  // LDS read element-offsets WITHIN one buffer (j-invariant)
  int kEo[4], kOo[4], vAo[4];
#pragma unroll
  for (int st = 0; st < 4; st++) {
    int rb = (st * 16 + l16) * 192;                    // 24 chunks * 8 el per row
    kEo[st] = rb + ((quad ^ x) * 8);                   // kk even: cg&7 = quad
    kOo[st] = rb + (((quad + 4) ^ x) * 8);             // kk odd:  cg&7 = quad+4
    vAo[st] = l16 * 64 + (((st * 2 + (quad >> 1)) ^ x) * 8) + (quad & 1) * 4;
  }

  f32x4 OaccS[8] = {}, OaccL[8] = {};
  float liS = 0.f, liL = 0.f;
  int mS = m0 + w * 16 + l16;
  int mL = mS + 64;

#if !HAVE_MFMA16
  int lA = l16 + ((quad & 1) << 5);
  int lB = lA + 16;
  bool lowq = (quad < 2);
  int vFo[2];
#pragma unroll
  for (int u = 0; u < 2; u++)
    vFo[u] = l16 * 64 + (((u * 4 + quad) ^ x) * 8);
#endif

#define STAGE(buf)                                                                         \
  do {                                                                                     \
    unsigned short* ksd = Ks + (buf) * (64 * 24 * 8);                                      \
    unsigned short* vsd = Vs + (buf) * (128 * 8 * 8);                                      \
    _Pragma("unroll")                                                                      \
    for (int k = 0; k < 6; k++) GL2LDS16(Kbase + koff[k], &ksd[(tid + k * 256) * 8]);      \
    _Pragma("unroll")                                                                      \
    for (int k = 0; k < 4; k++) GL2LDS16(Vbase + voff[k], &vsd[(tid + k * 256) * 8]);      \
    _Pragma("unroll")                                                                      \
    for (int k = 0; k < 6; k++) koff[k] += BN * DQK;                                       \
    _Pragma("unroll")                                                                      \
    for (int k = 0; k < 4; k++) voff[k] += BN;                                             \
  } while (0)

// raw barrier: own loads drained (vmcnt), then block-sync, then fence the scheduler so
// no LDS access of the next phase is hoisted above the barrier (guide rule #18).
#define PIPE_BARRIER()                                                                     \
  do {                                                                                     \
    asm volatile("s_waitcnt vmcnt(0)" ::: "memory");                                       \
    __builtin_amdgcn_s_barrier();                                                          \
    __builtin_amdgcn_sched_barrier(0);                                                     \
  } while (0)

  // prologue: stage tile 0 into buffer 0, drain, sync
  STAGE(0);
  PIPE_BARRIER();

  int cur = 0;
  for (int j = 0; j < NT; ++j) {
    // issue next-tile prefetch into the other buffer (in flight across the compute)
    if (j + 1 < NT) STAGE(cur ^ 1);

    const unsigned short* KsB = Ks + cur * (64 * 24 * 8);
    const unsigned short* VsB = Vs + cur * (128 * 8 * 8);

    // S^T = K Q^T for both q-sets: C-layout col = m_q (l16), row = s (quad*4+r), per st
    f32x4 ScS[4] = {}, ScL[4] = {};
#pragma unroll
    for (int kk = 0; kk < 6; kk++) {
#pragma unroll
      for (int st = 0; st < 4; st++) {
        bf16x8 kb = *(const bf16x8*)(KsB + ((kk & 1) ? kOo[st] : kEo[st]) + (kk >> 1) * 64);
        ScS[st] = __builtin_amdgcn_mfma_f32_16x16x32_bf16(kb, qfS[kk], ScS[st], 0, 0, 0);
        ScL[st] = __builtin_amdgcn_mfma_f32_16x16x32_bf16(kb, qfL[kk], ScL[st], 0, 0, 0);
      }
    }

    // causal masks: set S diagonal at j==diagA (fully masked at j==diagB);
    // set L diagonal at j==diagB.
    int n0 = j * BN;
    if (j >= diagA) {
#pragma unroll
      for (int st = 0; st < 4; st++)
#pragma unroll
        for (int r = 0; r < 4; r++) {
          int s = n0 + st * 16 + quad * 4 + r;
          if (s > mS) ScS[st][r] = -1e30f;
        }
    }
    if (j == diagB) {
#pragma unroll
      for (int st = 0; st < 4; st++)
#pragma unroll
        for (int r = 0; r < 4; r++) {
          int s = n0 + st * 16 + quad * 4 + r;
          if (s > mL) ScL[st][r] = -1e30f;
        }
    }

    // exp + row-sum partials + pack to bf16 pairs (truncation via v_perm)
    unsigned p0S[4], p1S[4], p0L[4], p1L[4];
#pragma unroll
    for (int st = 0; st < 4; st++) {
      float e0 = __expf(ScS[st][0]);
      float e1 = __expf(ScS[st][1]);
      float e2 = __expf(ScS[st][2]);
      float e3 = __expf(ScS[st][3]);
      liS += (e0 + e1) + (e2 + e3);
      p0S[st] = __builtin_amdgcn_perm(__builtin_bit_cast(unsigned, e1),
                                      __builtin_bit_cast(unsigned, e0), 0x07060302u);
      p1S[st] = __builtin_amdgcn_perm(__builtin_bit_cast(unsigned, e3),
                                      __builtin_bit_cast(unsigned, e2), 0x07060302u);
      float f0 = __expf(ScL[st][0]);
      float f1 = __expf(ScL[st][1]);
      float f2 = __expf(ScL[st][2]);
      float f3 = __expf(ScL[st][3]);
      liL += (f0 + f1) + (f2 + f3);
      p0L[st] = __builtin_amdgcn_perm(__builtin_bit_cast(unsigned, f1),
                                      __builtin_bit_cast(unsigned, f0), 0x07060302u);
      p1L[st] = __builtin_amdgcn_perm(__builtin_bit_cast(unsigned, f3),
                                      __builtin_bit_cast(unsigned, f2), 0x07060302u);
    }

#if HAVE_MFMA16
    // O^T += V^T P^T with K=16 mfma; each V fragment read once, feeds both q-sets
#pragma unroll
    for (int st = 0; st < 4; st++) {
      uint2 puS; puS.x = p0S[st]; puS.y = p1S[st];
      s16x4 pbS = __builtin_bit_cast(s16x4, puS);
      uint2 puL; puL.x = p0L[st]; puL.y = p1L[st];
      s16x4 pbL = __builtin_bit_cast(s16x4, puL);
#pragma unroll
      for (int dt = 0; dt < 8; dt++) {
        s16x4 va = __builtin_bit_cast(s16x4, *(const uint2*)(VsB + vAo[st] + dt * 1024));
        OaccS[dt] = mfma16(va, pbS, OaccS[dt]);
        OaccL[dt] = mfma16(va, pbL, OaccL[dt]);
      }
    }
#else
    // fallback: bpermute transpose + K=32 PV (both sets)
#pragma unroll
    for (int u = 0; u < 2; u++) {
      int a0 = __shfl((int)p0S[2 * u], lA, 64);
      int a1 = __shfl((int)p0S[2 * u + 1], lA, 64);
      int b0 = __shfl((int)p1S[2 * u], lA, 64);
      int b1 = __shfl((int)p1S[2 * u + 1], lA, 64);
      int c0 = __shfl((int)p0S[2 * u], lB, 64);
      int c1 = __shfl((int)p0S[2 * u + 1], lB, 64);
      int d0 = __shfl((int)p1S[2 * u], lB, 64);
      int d1 = __shfl((int)p1S[2 * u + 1], lB, 64);
      int4 pkS;
      pkS.x = lowq ? a0 : a1; pkS.y = lowq ? b0 : b1;
      pkS.z = lowq ? c0 : c1; pkS.w = lowq ? d0 : d1;
      bf16x8 pbS = __builtin_bit_cast(bf16x8, pkS);
      int sa0 = __shfl((int)p0L[2 * u], lA, 64);
      int sa1 = __shfl((int)p0L[2 * u + 1], lA, 64);
      int sb0 = __shfl((int)p1L[2 * u], lA, 64);
      int sb1 = __shfl((int)p1L[2 * u + 1], lA, 64);
      int sc0 = __shfl((int)p0L[2 * u], lB, 64);
      int sc1 = __shfl((int)p0L[2 * u + 1], lB, 64);
      int sd0 = __shfl((int)p1L[2 * u], lB, 64);
      int sd1 = __shfl((int)p1L[2 * u + 1], lB, 64);
      int4 pkL;
      pkL.x = lowq ? sa0 : sa1; pkL.y = lowq ? sb0 : sb1;
      pkL.z = lowq ? sc0 : sc1; pkL.w = lowq ? sd0 : sd1;
      bf16x8 pbL = __builtin_bit_cast(bf16x8, pkL);
#pragma unroll
      for (int dt = 0; dt < 8; dt++) {
        bf16x8 va = *(const bf16x8*)(VsB + vFo[u] + dt * 1024);
        OaccS[dt] = __builtin_amdgcn_mfma_f32_16x16x32_bf16(va, pbS, OaccS[dt], 0, 0, 0);
        OaccL[dt] = __builtin_amdgcn_mfma_f32_16x16x32_bf16(va, pbL, OaccL[dt], 0, 0, 0);
      }
    }
#endif

    // single barrier per tile: own prefetch drained (cheap: it had ~full tile of
    // compute to land), then all waves done reading buf `cur` -> safe to overwrite.
    PIPE_BARRIER();
    cur ^= 1;
  }

  // reduce li across the 4 quads (each lane holds partial for its m_q = l16 column)
  liS += __shfl_xor(liS, 16, 64);
  liS += __shfl_xor(liS, 32, 64);
  liL += __shfl_xor(liL, 16, 64);
  liL += __shfl_xor(liL, 32, 64);

  // epilogue: attn[t][h*128 + d] = O^T[d][m_q] / li
  float invS = 1.f / liS;
  float invL = 1.f / liL;
  unsigned short* dstS = attn + (size_t)mS * HID_DIM + h * DV + quad * 4;
  unsigned short* dstL = attn + (size_t)mL * HID_DIM + h * DV + quad * 4;
#pragma unroll
  for (int dt = 0; dt < 8; dt++) {
    unsigned lo = (unsigned)f2b(OaccS[dt][0] * invS) |
                  ((unsigned)f2b(OaccS[dt][1] * invS) << 16);
    unsigned hi = (unsigned)f2b(OaccS[dt][2] * invS) |
                  ((unsigned)f2b(OaccS[dt][3] * invS) << 16);
    uint2 pkv = {lo, hi};
    *(uint2*)(dstS + dt * 16) = pkv;
    unsigned lo2 = (unsigned)f2b(OaccL[dt][0] * invL) |
                   ((unsigned)f2b(OaccL[dt][1] * invL) << 16);
    unsigned hi2 = (unsigned)f2b(OaccL[dt][2] * invL) |
                   ((unsigned)f2b(OaccL[dt][3] * invL) << 16);
    uint2 pkv2 = {lo2, hi2};
    *(uint2*)(dstL + dt * 16) = pkv2;
  }
#undef STAGE
#undef PIPE_BARRIER
}

extern "C" void kernel_launch(void* const* d_in, const int* in_sizes, int n_in,
                              void* d_out, int out_size, void* d_ws, size_t ws_size,
                              hipStream_t stream) {
  const int*   positions = (const int*)d_in[0];
  const float* hs   = (const float*)d_in[1];
  const float* Wq   = (const float*)d_in[2];
  const float* Wkva = (const float*)d_in[3];
  const float* lnw  = (const float*)d_in[4];
  const float* Wkvb = (const float*)d_in[5];
  const float* Wo   = (const float*)d_in[6];
  float* out = (float*)d_out;

  char* p = (char*)d_ws;
  size_t off = 0;
  auto alloc = [&](size_t bytes) {
    char* r = p + off;
    off = (off + bytes + 255) & ~(size_t)255;
    return r;
  };
  unsigned short* hsb     = (unsigned short*)alloc((size_t)T_LEN * HID_DIM * 2);
  unsigned short* WqT     = (unsigned short*)alloc((size_t)(NH * DQK) * HID_DIM * 2);
  unsigned short* WkvaT   = (unsigned short*)alloc((size_t)(LKV + DROPE) * HID_DIM * 2);
  unsigned short* WkvbT   = (unsigned short*)alloc((size_t)(NH * 256) * LKV * 2);
  unsigned short* WoT     = (unsigned short*)alloc((size_t)HID_DIM * HID_DIM * 2);
  unsigned short* Qh      = (unsigned short*)alloc((size_t)NH * T_LEN * DQK * 2);
  unsigned short* kva     = (unsigned short*)alloc((size_t)T_LEN * LKV * 2);
  unsigned short* Kh      = (unsigned short*)alloc((size_t)NH * T_LEN * DQK * 2);
  unsigned short* VT      = (unsigned short*)alloc((size_t)NH * DV * T_LEN * 2);
  unsigned short* attn    = (unsigned short*)alloc((size_t)T_LEN * HID_DIM * 2);
  float*          latentf = (float*)alloc((size_t)T_LEN * (LKV + DROPE) * 4);

  // --- stage 0: all weight transposes + fused hs cvt (one launch) ---
  k_transpose_all<<<17536, dim3(32, 8), 0, stream>>>(Wq, Wkva, Wkvb, Wo, hs,
                                                     WqT, WkvaT, WkvbT, WoT, hsb);

  // --- stage 1: merged Wq (rope fused) + Wkva projections (XCD-swizzled, BK=64 dbuf) ---
  k_gemm_proj<<<dim3(29, T_LEN / 128), 256, 0, stream>>>(hsb, WqT, WkvaT, positions, Qh, latentf);

  // --- stage 2: rmsnorm + k_pe rope prep (wave-per-row) ---
  k_prep_latent<<<T_LEN / 4, 256, 0, stream>>>(latentf, lnw, positions, kva, Kh);

  // --- stage 3: kv projection with fused scatter -> Kh nope / V^T (XCD-swizzled, dbuf) ---
  k_gemm_wkvb<<<dim3((NH * 256) / 128, T_LEN / 128), 256, 0, stream>>>(kva, WkvbT, Kh, VT);

  // --- stage 4: fused flash attention (dual q-set, true async double-buffer) ---
  k_flash<<<dim3(512), 256, 0, stream>>>(Qh, Kh, VT, attn);

  // --- stage 5: out = attn @ Wo -> f32 (XCD-swizzled, BK=64 dbuf) ---
  k_gemm128<<<dim3(HID_DIM / 128, T_LEN / 128), 256, 0, stream>>>(
      attn, WoT, out, HID_DIM, HID_DIM, HID_DIM, HID_DIM, HID_DIM);
}